// Round 17
// baseline (3096.199 us; speedup 1.0000x reference)
//
#include <hip/hip_runtime.h>
#include <math.h>

#define MAXIT 16      // wavefronts 0..15 (max in-degree ~13 for Poisson(2))
#define MAXDEG 16     // per-parent bucket capacity for ranking

typedef __attribute__((ext_vector_type(8))) short bf16x8;
typedef __attribute__((ext_vector_type(16))) float f32x16;

static inline int imin(int a, int b) { return a < b ? a : b; }

__device__ __forceinline__ float sigm(float v) { return 1.0f / (1.0f + __expf(-v)); }
__device__ __forceinline__ float tfast(float v) {
  float vc = fminf(fmaxf(v, -20.0f), 20.0f);
  float t = __expf(2.0f * vc);
  return (t - 1.0f) / (t + 1.0f);
}
__device__ __forceinline__ unsigned short f2bf(float f) {
  unsigned int u = __float_as_uint(f);
  u += 0x7FFFu + ((u >> 16) & 1u);
  return (unsigned short)(u >> 16);
}
__device__ __forceinline__ float bf2f(unsigned short s) {
  return __uint_as_float(((unsigned int)s) << 16);
}
__device__ __forceinline__ unsigned bfadd2(unsigned x, unsigned y) {
  float sl = bf2f((unsigned short)(x & 0xFFFFu)) + bf2f((unsigned short)(y & 0xFFFFu));
  float sh = bf2f((unsigned short)(x >> 16)) + bf2f((unsigned short)(y >> 16));
  return (unsigned)f2bf(sl) | ((unsigned)f2bf(sh) << 16);
}
__device__ __forceinline__ uint4 bfadd8(uint4 a, uint4 b) {
  return make_uint4(bfadd2(a.x, b.x), bfadd2(a.y, b.y), bfadd2(a.z, b.z), bfadd2(a.w, b.w));
}

// ---------------- fills ----------------
__global__ void kzero16(uint4* p, size_t n) {
  size_t i = (size_t)blockIdx.x * blockDim.x + threadIdx.x;
  size_t st = (size_t)gridDim.x * blockDim.x;
  uint4 z = make_uint4(0u, 0u, 0u, 0u);
  for (; i < n; i += st) p[i] = z;
}
__global__ void kzeroi(int* p, int n) {
  int i = blockIdx.x * blockDim.x + threadIdx.x;
  if (i < n) p[i] = 0;
}
__global__ void kfill(float* p, size_t n, float v) {
  size_t i = (size_t)blockIdx.x * blockDim.x + threadIdx.x;
  size_t st = (size_t)gridDim.x * blockDim.x;
  for (; i < n; i += st) p[i] = v;
}

// ---------------- graph precompute ----------------
__global__ void k_histo(const int* __restrict__ par, int E,
                        int* __restrict__ node_order, int* __restrict__ bucket) {
  int e = blockIdx.x * blockDim.x + threadIdx.x;
  if (e >= E) return;
  int p = par[e];
  int slot = atomicAdd(&node_order[p], 1);
  if (slot < MAXDEG) bucket[(size_t)p * MAXDEG + slot] = e;
}

__global__ void k_rank(const int* __restrict__ par, int E, int N,
                       const int* __restrict__ node_order, const int* __restrict__ bucket,
                       int* __restrict__ edgeCnt, int* __restrict__ edgeList) {
  __shared__ int lcnt[MAXIT], lbase[MAXIT];
  const int t = threadIdx.x;
  if (t < MAXIT) lcnt[t] = 0;
  __syncthreads();
  int e = blockIdx.x * blockDim.x + t;
  int r = 0, ls = 0;
  if (e < E) {
    int p = par[e];
    int d = node_order[p]; if (d > MAXDEG) d = MAXDEG;
    int rr = 1;
    for (int j = 0; j < d; ++j) rr += (bucket[(size_t)p * MAXDEG + j] < e) ? 1 : 0;
    if (rr < MAXIT) { r = rr; ls = atomicAdd(&lcnt[rr], 1); }
  }
  __syncthreads();
  if (t < MAXIT && lcnt[t] > 0) lbase[t] = atomicAdd(&edgeCnt[t], lcnt[t]);
  __syncthreads();
  if (r > 0) edgeList[(size_t)r * N + lbase[r] + ls] = e;
}

__global__ void k_nodelist(int N, const int* __restrict__ node_order,
                           int* __restrict__ nodeCnt, int* __restrict__ nodeList) {
  __shared__ int lcnt[MAXIT], lbase[MAXIT];
  const int t = threadIdx.x;
  if (t < MAXIT) lcnt[t] = 0;
  __syncthreads();
  int v = blockIdx.x * blockDim.x + t;
  int n = -1, ls = 0;
  if (v < N) {
    n = node_order[v]; if (n >= MAXIT) n = MAXIT - 1;
    ls = atomicAdd(&lcnt[n], 1);
  }
  __syncthreads();
  if (t < MAXIT && lcnt[t] > 0) lbase[t] = atomicAdd(&nodeCnt[t], lcnt[t]);
  __syncthreads();
  if (n >= 0) nodeList[(size_t)n * N + lbase[n] + ls] = v;
}

// ---------------- x -> bf16 mirror ----------------
__global__ void k_pack_x(const float* __restrict__ x, unsigned short* __restrict__ xb, size_t n8) {
  size_t i = (size_t)blockIdx.x * blockDim.x + threadIdx.x;
  size_t st = (size_t)gridDim.x * blockDim.x;
  for (; i < n8; i += st) {
    const float* p = x + i * 8;
    float4 f0 = *(const float4*)p, f1 = *(const float4*)(p + 4);
    uint4 r;
    r.x = (unsigned)f2bf(f0.x) | ((unsigned)f2bf(f0.y) << 16);
    r.y = (unsigned)f2bf(f0.z) | ((unsigned)f2bf(f0.w) << 16);
    r.z = (unsigned)f2bf(f1.x) | ((unsigned)f2bf(f1.y) << 16);
    r.w = (unsigned)f2bf(f1.z) | ((unsigned)f2bf(f1.w) << 16);
    *(uint4*)(xb + i * 8) = r;
  }
}

// ---------------- weight packs ----------------
// iou K=1024 pack (R12-verified): uint4 index = ((jc*64 + s)*3 + g)*64 + lane
__global__ void k_pack_biou(const float* __restrict__ W, const float* __restrict__ U,
                            unsigned short* __restrict__ Bpk) {
  int i = blockIdx.x * blockDim.x + threadIdx.x;
  if (i >= 16 * 64 * 3 * 64) return;
  int lane = i & 63;
  int q = i >> 6;
  int g = q % 3; q /= 3;
  int s = q & 63;
  int jc = q >> 6;
  int col = jc * 32 + (lane & 31);
  int k0 = s * 16 + (lane >> 5) * 8;
  int rowW = g * 512 + col;
  unsigned short v[8];
#pragma unroll
  for (int j = 0; j < 8; ++j) {
    int kk = k0 + j;
    v[j] = f2bf(kk < 512 ? W[(size_t)rowW * 512 + kk] : U[(size_t)rowW * 512 + kk - 512]);
  }
  *(uint4*)(Bpk + (size_t)i * 8) = *(uint4*)v;
}

// 512x512 single-matrix pack (used for U_f and W_f): index = (jc*32+s)*64+lane
__global__ void k_pack_m512(const float* __restrict__ M, unsigned short* __restrict__ Bpk) {
  int i = blockIdx.x * blockDim.x + threadIdx.x;
  if (i >= 16 * 32 * 64) return;
  int lane = i & 63;
  int q = i >> 6;
  int s = q & 31;
  int jc = q >> 5;
  int col = jc * 32 + (lane & 31);
  int k0 = s * 16 + (lane >> 5) * 8;
  unsigned short v[8];
#pragma unroll
  for (int j = 0; j < 8; ++j) v[j] = f2bf(M[(size_t)col * 512 + k0 + j]);
  *(uint4*)(Bpk + (size_t)i * 8) = *(uint4*)v;
}

// ---------------- fused: addfc(n-1) for deg>n-1 parents + hsumb(n) ----------------
__global__ void k_edge_pre(int n, int N, const int* __restrict__ edgeCnt, const int* __restrict__ edgeList,
                           const int* __restrict__ par, const int* __restrict__ chd,
                           const int* __restrict__ node_order,
                           const unsigned short* __restrict__ hb, unsigned short* __restrict__ hsumb,
                           const unsigned short* __restrict__ fc, float* __restrict__ c) {
  const int cntH = edgeCnt[n];
  const int cntA = (n >= 2) ? edgeCnt[n - 1] : 0;
  const size_t totH = (size_t)cntH * 64;
  const size_t total = totH + (size_t)cntA * 64;
  size_t st = (size_t)gridDim.x * blockDim.x;
  for (size_t i = (size_t)blockIdx.x * blockDim.x + threadIdx.x; i < total; i += st) {
    if (i < totH) {
      int slot = (int)(i >> 6), j8 = ((int)i & 63) << 3;
      int e = edgeList[(size_t)n * N + slot];
      int p = par[e], ch = chd[e];
      uint4 hv = *(const uint4*)&hb[(size_t)ch * 512 + j8];
      if (n == 1) {
        *(uint4*)&hsumb[(size_t)p * 512 + j8] = hv;
      } else {
        uint4 hs = *(const uint4*)&hsumb[(size_t)p * 512 + j8];
        *(uint4*)&hsumb[(size_t)p * 512 + j8] = bfadd8(hs, hv);
      }
    } else {
      size_t k = i - totH;
      int slot = (int)(k >> 6), j8 = ((int)k & 63) << 3;
      int e = edgeList[(size_t)(n - 1) * N + slot];
      int p = par[e];
      if (node_order[p] <= n - 1) continue;   // deg==n-1 handled in iou epilogue
      size_t base = (size_t)p * 512 + j8;
      uint4 f8 = *(const uint4*)&fc[base];
      unsigned fw[4] = {f8.x, f8.y, f8.z, f8.w};
      float4 c0 = *(const float4*)&c[base];
      float4 c1 = *(const float4*)&c[base + 4];
      c0.x += bf2f((unsigned short)(fw[0] & 0xFFFFu)); c0.y += bf2f((unsigned short)(fw[0] >> 16));
      c0.z += bf2f((unsigned short)(fw[1] & 0xFFFFu)); c0.w += bf2f((unsigned short)(fw[1] >> 16));
      c1.x += bf2f((unsigned short)(fw[2] & 0xFFFFu)); c1.y += bf2f((unsigned short)(fw[2] >> 16));
      c1.z += bf2f((unsigned short)(fw[3] & 0xFFFFu)); c1.w += bf2f((unsigned short)(fw[3] >> 16));
      *(float4*)&c[base] = c0;
      *(float4*)&c[base + 4] = c1;
    }
  }
}

// ---------------- iou GEMM (R12 k_gemm9, modes 0/1 only; verified no-spill) ----------------
template<int MODE>
__global__ __launch_bounds__(256, 2)
void k_gemm9(int n, int N, const int* __restrict__ cntArr, const int* __restrict__ list,
             const unsigned short* __restrict__ xb, const unsigned short* __restrict__ hsrc,
             const unsigned short* __restrict__ Bpk,
             const float* __restrict__ bW, const float* __restrict__ bU,
             float* __restrict__ c, float* __restrict__ h, unsigned short* __restrict__ hb,
             unsigned short* __restrict__ fc) {
  const int cnt = cntArr[n];
  if (cnt == 0) return;
  constexpr int KS    = (MODE == 0) ? 32 : 64;
  constexpr int KC8   = KS * 2;
  constexpr int GATES = 3;
  constexpr int D     = 4;
  const int rowTiles = (cnt + 31) >> 5;

  __shared__ uint4 lA4[KS * 64];
  __shared__ int ids0[32];
  const int t = threadIdx.x, lane = t & 63, w = t >> 6;

  auto ldA = [&](int s) -> bf16x8 {
    int hk = lane >> 5, rl = lane & 31;
    return *(const bf16x8*)&lA4[s * 64 + hk * 32 + (rl ^ ((2 * s + hk) & 31))];
  };

  for (int tile = blockIdx.x; tile < rowTiles; tile += gridDim.x) {
    __syncthreads();
    if (t < 32) {
      int r = (tile << 5) + t;
      ids0[t] = (r < cnt) ? list[(size_t)n * N + r] : -1;
    }
    __syncthreads();

    constexpr int ITERS = (32 * KC8) / 256;
#pragma unroll
    for (int i = 0; i < ITERS; ++i) {
      int cid = i * 256 + t;
      int row = cid >> ((MODE == 0) ? 6 : 7);
      int kc8 = cid & (KC8 - 1);
      int id0 = ids0[row];
      int id = id0 < 0 ? 0 : id0;
      uint4 v;
      if (MODE == 0 || kc8 < 64) {
        v = *(const uint4*)(xb + (size_t)id * 512 + (kc8 << 3));
      } else {
        v = *(const uint4*)(hsrc + (size_t)id * 512 + ((kc8 - 64) << 3));
      }
      int s = kc8 >> 1, hk = kc8 & 1;
      lA4[s * 64 + hk * 32 + (row ^ (kc8 & 31))] = v;
    }
    __syncthreads();

    for (int p = 0; p < 4; ++p) {
      const int jc = p * 4 + w;
      const uint4* bb = (const uint4*)Bpk + (size_t)jc * 64 * GATES * 64 + lane;

      f32x16 acc[GATES];
#pragma unroll
      for (int g = 0; g < GATES; ++g)
#pragma unroll
        for (int q = 0; q < 16; ++q) acc[g][q] = 0.f;

      bf16x8 aP[D];
      uint4 bP[D][GATES];
#pragma unroll
      for (int d = 0; d < D; ++d) {
        aP[d] = ldA(d);
#pragma unroll
        for (int g = 0; g < GATES; ++g)
          bP[d][g] = bb[(size_t)(d * GATES + g) * 64];
      }
      for (int s0 = 0; s0 < KS - D; s0 += D) {
#pragma unroll
        for (int d = 0; d < D; ++d) {
#pragma unroll
          for (int g = 0; g < GATES; ++g)
            acc[g] = __builtin_amdgcn_mfma_f32_32x32x16_bf16(
                aP[d], *(bf16x8*)&bP[d][g], acc[g], 0, 0, 0);
          aP[d] = ldA(s0 + D + d);
#pragma unroll
          for (int g = 0; g < GATES; ++g)
            bP[d][g] = bb[(size_t)((s0 + D + d) * GATES + g) * 64];
        }
      }
#pragma unroll
      for (int d = 0; d < D; ++d)
#pragma unroll
        for (int g = 0; g < GATES; ++g)
          acc[g] = __builtin_amdgcn_mfma_f32_32x32x16_bf16(
              aP[d], *(bf16x8*)&bP[d][g], acc[g], 0, 0, 0);

      const int jh = jc * 32 + (lane & 31);
      float bi = bW[jh], bo = bW[512 + jh], bu = bW[1024 + jh];
      if (MODE == 1) { bi += bU[jh]; bo += bU[512 + jh]; bu += bU[1024 + jh]; }
#pragma unroll
      for (int reg = 0; reg < 16; ++reg) {
        int rl = ((lane >> 5) << 2) + (reg & 3) + ((reg >> 2) << 3);
        int node = ids0[rl];
        if (node < 0) continue;
        size_t base = (size_t)node * 512 + jh;
        float iv = acc[0][reg] + bi;
        float ov = acc[1][reg] + bo;
        float uv = acc[2][reg] + bu;
        float fcv = (MODE == 1) ? bf2f(fc[base]) : 0.f;
        float cn = sigm(iv) * tfast(uv) + fcv;
        c[base] = cn;
        float hv = sigm(ov) * tfast(cn);
        h[base] = hv;
        hb[base] = f2bf(hv);
      }
    }
  }
}

// ---------------- prologue dense GEMM: pxF[v] = x[v] @ W_f^T (bf16, d_out overlay) ----------------
// Sequential rows (no gather). NSTR=2 / D=4 = R12 MODE2 register shape (no-spill verified).
__global__ __launch_bounds__(256, 2)
void k_pxf(int N, const float* __restrict__ x, const unsigned short* __restrict__ Bpk,
           unsigned short* __restrict__ pxF) {
  const int rowTiles = (N + 31) >> 5;
  __shared__ uint4 lA4[32 * 64];                 // 32 KB
  const int t = threadIdx.x, lane = t & 63, w = t >> 6;

  auto ldA = [&](int s) -> bf16x8 {
    int hk = lane >> 5, rl = lane & 31;
    return *(const bf16x8*)&lA4[s * 64 + hk * 32 + (rl ^ ((2 * s + hk) & 31))];
  };

  for (int tile = blockIdx.x; tile < rowTiles; tile += gridDim.x) {
    __syncthreads();
#pragma unroll
    for (int i = 0; i < 8; ++i) {
      int cid = i * 256 + t;
      int row = cid >> 6;
      int kc8 = cid & 63;
      int grow = (tile << 5) + row;
      if (grow >= N) grow = N - 1;
      const float* p = x + (size_t)grow * 512 + (kc8 << 3);
      float4 f0 = *(const float4*)p, f1 = *(const float4*)(p + 4);
      uint4 v;
      v.x = (unsigned)f2bf(f0.x) | ((unsigned)f2bf(f0.y) << 16);
      v.y = (unsigned)f2bf(f0.z) | ((unsigned)f2bf(f0.w) << 16);
      v.z = (unsigned)f2bf(f1.x) | ((unsigned)f2bf(f1.y) << 16);
      v.w = (unsigned)f2bf(f1.z) | ((unsigned)f2bf(f1.w) << 16);
      int s = kc8 >> 1, hk = kc8 & 1;
      lA4[s * 64 + hk * 32 + (row ^ (kc8 & 31))] = v;
    }
    __syncthreads();

    for (int p = 0; p < 2; ++p) {
      const uint4* bb[2];
#pragma unroll
      for (int str = 0; str < 2; ++str) {
        int jc = p * 8 + str * 4 + w;
        bb[str] = (const uint4*)Bpk + (size_t)jc * 32 * 64 + lane;
      }
      f32x16 acc[2];
#pragma unroll
      for (int str = 0; str < 2; ++str)
#pragma unroll
        for (int q = 0; q < 16; ++q) acc[str][q] = 0.f;

      bf16x8 aP[4];
      uint4 bP[4][2];
#pragma unroll
      for (int d = 0; d < 4; ++d) {
        aP[d] = ldA(d);
#pragma unroll
        for (int str = 0; str < 2; ++str) bP[d][str] = bb[str][(size_t)d * 64];
      }
      for (int s0 = 0; s0 < 28; s0 += 4) {
#pragma unroll
        for (int d = 0; d < 4; ++d) {
#pragma unroll
          for (int str = 0; str < 2; ++str)
            acc[str] = __builtin_amdgcn_mfma_f32_32x32x16_bf16(
                aP[d], *(bf16x8*)&bP[d][str], acc[str], 0, 0, 0);
          aP[d] = ldA(s0 + 4 + d);
#pragma unroll
          for (int str = 0; str < 2; ++str) bP[d][str] = bb[str][(size_t)(s0 + 4 + d) * 64];
        }
      }
#pragma unroll
      for (int d = 0; d < 4; ++d)
#pragma unroll
        for (int str = 0; str < 2; ++str)
          acc[str] = __builtin_amdgcn_mfma_f32_32x32x16_bf16(
              aP[d], *(bf16x8*)&bP[d][str], acc[str], 0, 0, 0);

#pragma unroll
      for (int str = 0; str < 2; ++str) {
        const int jh = (p * 8 + str * 4 + w) * 32 + (lane & 31);
#pragma unroll
        for (int reg = 0; reg < 16; ++reg) {
          int rl = ((lane >> 5) << 2) + (reg & 3) + ((reg >> 2) << 3);
          int grow = (tile << 5) + rl;
          if (grow < N) pxF[(size_t)grow * 1024 + jh] = f2bf(acc[str][reg]);
        }
      }
    }
  }
}

// ---------------- f GEMM, K=512 (hb[chd] only; x-half hoisted into pxF) ----------------
// fc[par] = sigm(hb[chd]@U_f + pxF[par] + bWf + bUf) * c[chd]
__global__ __launch_bounds__(256, 2)
void k_gemmF5(int n, int N, const int* __restrict__ edgeCnt, const int* __restrict__ edgeList,
              const int* __restrict__ par, const int* __restrict__ chd,
              const unsigned short* __restrict__ hb, const unsigned short* __restrict__ Bpk,
              const unsigned short* __restrict__ pxF,
              const float* __restrict__ bWf, const float* __restrict__ bUf,
              const float* __restrict__ c, unsigned short* __restrict__ fc) {
  const int cnt = edgeCnt[n];
  if (cnt == 0) return;
  constexpr int D = 4;
  const int rowTiles = (cnt + 31) >> 5;

  __shared__ uint4 lA4[32 * 64];                 // 32 KB
  __shared__ int ids0[32], ids1[32];
  const int t = threadIdx.x, lane = t & 63, w = t >> 6;

  auto ldA = [&](int s) -> bf16x8 {
    int hk = lane >> 5, rl = lane & 31;
    return *(const bf16x8*)&lA4[s * 64 + hk * 32 + (rl ^ ((2 * s + hk) & 31))];
  };

  for (int tile = blockIdx.x; tile < rowTiles; tile += gridDim.x) {
    __syncthreads();
    if (t < 32) {
      int r = (tile << 5) + t;
      int idx = (r < cnt) ? edgeList[(size_t)n * N + r] : -1;
      ids0[t] = idx >= 0 ? par[idx] : -1;
      ids1[t] = idx >= 0 ? chd[idx] : 0;
    }
    __syncthreads();

    // stage A: hb[chd], 32 rows x 512 bf16
#pragma unroll
    for (int i = 0; i < 8; ++i) {
      int cid = i * 256 + t;
      int row = cid >> 6;
      int kc8 = cid & 63;
      int id = ids1[row];
      uint4 v = *(const uint4*)(hb + (size_t)id * 512 + (kc8 << 3));
      int s = kc8 >> 1, hk = kc8 & 1;
      lA4[s * 64 + hk * 32 + (row ^ (kc8 & 31))] = v;
    }
    __syncthreads();

    for (int p = 0; p < 2; ++p) {
      const uint4* bb[2];
#pragma unroll
      for (int str = 0; str < 2; ++str) {
        int jc = p * 8 + str * 4 + w;
        bb[str] = (const uint4*)Bpk + (size_t)jc * 32 * 64 + lane;
      }
      f32x16 acc[2];
#pragma unroll
      for (int str = 0; str < 2; ++str)
#pragma unroll
        for (int q = 0; q < 16; ++q) acc[str][q] = 0.f;

      bf16x8 aP[D];
      uint4 bP[D][2];
#pragma unroll
      for (int d = 0; d < D; ++d) {
        aP[d] = ldA(d);
#pragma unroll
        for (int str = 0; str < 2; ++str) bP[d][str] = bb[str][(size_t)d * 64];
      }
      for (int s0 = 0; s0 < 32 - D; s0 += D) {
#pragma unroll
        for (int d = 0; d < D; ++d) {
#pragma unroll
          for (int str = 0; str < 2; ++str)
            acc[str] = __builtin_amdgcn_mfma_f32_32x32x16_bf16(
                aP[d], *(bf16x8*)&bP[d][str], acc[str], 0, 0, 0);
          aP[d] = ldA(s0 + D + d);
#pragma unroll
          for (int str = 0; str < 2; ++str) bP[d][str] = bb[str][(size_t)(s0 + D + d) * 64];
        }
      }
#pragma unroll
      for (int d = 0; d < D; ++d)
#pragma unroll
        for (int str = 0; str < 2; ++str)
          acc[str] = __builtin_amdgcn_mfma_f32_32x32x16_bf16(
              aP[d], *(bf16x8*)&bP[d][str], acc[str], 0, 0, 0);

#pragma unroll
      for (int str = 0; str < 2; ++str) {
        const int jh = (p * 8 + str * 4 + w) * 32 + (lane & 31);
        float bfv = bWf[jh] + bUf[jh];
#pragma unroll
        for (int reg = 0; reg < 16; ++reg) {
          int rl = ((lane >> 5) << 2) + (reg & 3) + ((reg >> 2) << 3);
          int pe = ids0[rl];
          if (pe < 0) continue;
          int ce = ids1[rl];
          float fv = sigm(acc[str][reg] + bf2f(pxF[(size_t)pe * 1024 + jh]) + bfv);
          fc[(size_t)pe * 512 + jh] = f2bf(fv * c[(size_t)ce * 512 + jh]);
        }
      }
    }
  }
}

// ---------------- driver ----------------
static void run_all(const float* x, const int* par, const int* chd,
                    const float* Wiou, const float* bWiou, const float* Uiou, const float* bUiou,
                    const float* Wf, const float* bWf, const float* Uf, const float* bUf,
                    float* h, int N, int E, void* d_ws, hipStream_t stream) {
  const size_t NV = (size_t)N * 512;
  char* cur = (char*)d_ws;
  auto take = [&](size_t bytes) -> char* {
    char* r = cur; cur += (bytes + 255) & ~(size_t)255; return r;
  };
  float* c             = (float*)take(NV * 4);
  unsigned short* hb   = (unsigned short*)take(NV * 2);
  unsigned short* hsumb= (unsigned short*)take(NV * 2);
  unsigned short* xb   = (unsigned short*)take(NV * 2);
  unsigned short* fc   = (unsigned short*)take(NV * 2);
  unsigned short* BpkI = (unsigned short*)take((size_t)16 * 64 * 3 * 64 * 8 * 2);
  unsigned short* BpkUF= (unsigned short*)take((size_t)16 * 32 * 64 * 8 * 2);
  unsigned short* BpkWF= (unsigned short*)take((size_t)16 * 32 * 64 * 8 * 2);
  int* node_order      = (int*)take((size_t)N * 4);
  int* nodeCnt         = (int*)take(MAXIT * 4);
  int* edgeCnt         = (int*)take(MAXIT * 4);
  int* bucket          = (int*)take((size_t)N * MAXDEG * 4);
  int* nodeList        = (int*)take((size_t)MAXIT * N * 4);
  int* edgeList        = (int*)take((size_t)MAXIT * N * 4);

  unsigned short* pxF = (unsigned short*)h;      // d_out overlay: first 1KB of each h row

  kzero16<<<2048, 256, 0, stream>>>((uint4*)c, NV * 4 / 16);
  kzero16<<<2048, 256, 0, stream>>>((uint4*)hb, NV * 2 / 16);
  kzeroi<<<(N + 255) / 256, 256, 0, stream>>>(node_order, N);
  kzeroi<<<1, 64, 0, stream>>>(nodeCnt, MAXIT);
  kzeroi<<<1, 64, 0, stream>>>(edgeCnt, MAXIT);

  k_pack_x<<<2048, 256, 0, stream>>>(x, xb, NV / 8);
  k_pack_biou<<<(16 * 64 * 3 * 64 + 255) / 256, 256, 0, stream>>>(Wiou, Uiou, BpkI);
  k_pack_m512<<<(16 * 32 * 64 + 255) / 256, 256, 0, stream>>>(Uf, BpkUF);
  k_pack_m512<<<(16 * 32 * 64 + 255) / 256, 256, 0, stream>>>(Wf, BpkWF);

  k_histo<<<(E + 255) / 256, 256, 0, stream>>>(par, E, node_order, bucket);
  k_rank<<<(E + 255) / 256, 256, 0, stream>>>(par, E, N, node_order, bucket, edgeCnt, edgeList);
  k_nodelist<<<(N + 255) / 256, 256, 0, stream>>>(N, node_order, nodeCnt, nodeList);

  // prologue: pxF = x @ W_f^T into d_out overlay (before any h writes)
  k_pxf<<<imin(4096, (N + 31) >> 5), 256, 0, stream>>>(N, x, BpkWF, pxF);

  // wavefront 0 (writes h for deg-0 nodes; their pxF is never read)
  {
    int g = imin(4096, (N + 31) >> 5);
    k_gemm9<0><<<g, 256, 0, stream>>>(0, N, nodeCnt, nodeList,
                                      xb, hsumb, BpkI, bWiou, bUiou, c, h, hb, fc);
  }
  for (int n = 1; n < MAXIT; ++n) {
    int boundE = E / n;
    int boundN = imin(N, boundE);
    int boundA = (n >= 2) ? (E / (n - 1)) : 0;
    int gE = imin(2048, (int)(((size_t)(boundE + boundA) * 64 + 255) / 256));
    int gF = imin(4096, (boundE + 31) >> 5);
    int gI = imin(4096, (boundN + 31) >> 5);
    k_edge_pre<<<gE, 256, 0, stream>>>(n, N, edgeCnt, edgeList, par, chd, node_order,
                                       hb, hsumb, fc, c);
    k_gemmF5<<<gF, 256, 0, stream>>>(n, N, edgeCnt, edgeList, par, chd,
                                     hb, BpkUF, pxF, bWf, bUf, c, fc);
    k_gemm9<1><<<gI, 256, 0, stream>>>(n, N, nodeCnt, nodeList,
                                       xb, hsumb, BpkI, bWiou, bUiou, c, h, hb, fc);
  }
}

extern "C" void kernel_launch(void* const* d_in, const int* in_sizes, int n_in,
                              void* d_out, int out_size, void* d_ws, size_t ws_size,
                              hipStream_t stream) {
  (void)n_in; (void)out_size;
  const float* x     = (const float*)d_in[0];
  const int*   ei    = (const int*)d_in[1];
  const float* Wiou  = (const float*)d_in[4];
  const float* bWiou = (const float*)d_in[5];
  const float* Uiou  = (const float*)d_in[6];
  const float* bUiou = (const float*)d_in[7];
  const float* Wf    = (const float*)d_in[8];
  const float* bWf   = (const float*)d_in[9];
  const float* Uf    = (const float*)d_in[10];
  const float* bUf   = (const float*)d_in[11];
  const int N = in_sizes[0] / 512;
  const int E = in_sizes[1] / 2;
  const int* par = ei;
  const int* chd = ei + E;
  float* h = (float*)d_out;

  const size_t NV = (size_t)N * 512;
  const size_t need = NV * 12 + (size_t)8 * 1024 * 1024 +
                      ((size_t)N * (1 + MAXDEG + 2 * MAXIT) + 512) * 4;

  if (ws_size >= need) {
    run_all(x, par, chd, Wiou, bWiou, Uiou, bUiou, Wf, bWf, Uf, bUf,
            h, N, E, d_ws, stream);
  } else {
    kfill<<<2048, 256, 0, stream>>>(h, NV, 1.0e6f);  // diagnostic sentinel: ws too small
  }
}

// Round 18
// 2553.729 us; speedup vs baseline: 1.2124x; 1.2124x over previous
//
#include <hip/hip_runtime.h>
#include <math.h>

#define MAXIT 16      // wavefronts 0..15 (max in-degree ~13 for Poisson(2))
#define MAXDEG 16     // per-parent bucket capacity for ranking

typedef __attribute__((ext_vector_type(8))) short bf16x8;
typedef __attribute__((ext_vector_type(16))) float f32x16;

static inline int imin(int a, int b) { return a < b ? a : b; }

__device__ __forceinline__ float sigm(float v) { return 1.0f / (1.0f + __expf(-v)); }
__device__ __forceinline__ float tfast(float v) {
  float vc = fminf(fmaxf(v, -20.0f), 20.0f);
  float t = __expf(2.0f * vc);
  return (t - 1.0f) / (t + 1.0f);
}
__device__ __forceinline__ unsigned short f2bf(float f) {
  unsigned int u = __float_as_uint(f);
  u += 0x7FFFu + ((u >> 16) & 1u);
  return (unsigned short)(u >> 16);
}
__device__ __forceinline__ float bf2f(unsigned short s) {
  return __uint_as_float(((unsigned int)s) << 16);
}
__device__ __forceinline__ unsigned bfadd2(unsigned x, unsigned y) {
  float sl = bf2f((unsigned short)(x & 0xFFFFu)) + bf2f((unsigned short)(y & 0xFFFFu));
  float sh = bf2f((unsigned short)(x >> 16)) + bf2f((unsigned short)(y >> 16));
  return (unsigned)f2bf(sl) | ((unsigned)f2bf(sh) << 16);
}
__device__ __forceinline__ uint4 bfadd8(uint4 a, uint4 b) {
  return make_uint4(bfadd2(a.x, b.x), bfadd2(a.y, b.y), bfadd2(a.z, b.z), bfadd2(a.w, b.w));
}

// async global->LDS, 16B per lane; lds base must be wave-uniform (HW adds lane*16)
__device__ __forceinline__ void gload_lds16(const unsigned short* g, void* l) {
  __builtin_amdgcn_global_load_lds(
      (const __attribute__((address_space(1))) unsigned int*)g,
      (__attribute__((address_space(3))) unsigned int*)l, 16, 0, 0);
}

// ---------------- fills ----------------
__global__ void kzero16(uint4* p, size_t n) {
  size_t i = (size_t)blockIdx.x * blockDim.x + threadIdx.x;
  size_t st = (size_t)gridDim.x * blockDim.x;
  uint4 z = make_uint4(0u, 0u, 0u, 0u);
  for (; i < n; i += st) p[i] = z;
}
__global__ void kzeroi(int* p, int n) {
  int i = blockIdx.x * blockDim.x + threadIdx.x;
  if (i < n) p[i] = 0;
}
__global__ void kfill(float* p, size_t n, float v) {
  size_t i = (size_t)blockIdx.x * blockDim.x + threadIdx.x;
  size_t st = (size_t)gridDim.x * blockDim.x;
  for (; i < n; i += st) p[i] = v;
}

// ---------------- graph precompute ----------------
__global__ void k_histo(const int* __restrict__ par, int E,
                        int* __restrict__ node_order, int* __restrict__ bucket) {
  int e = blockIdx.x * blockDim.x + threadIdx.x;
  if (e >= E) return;
  int p = par[e];
  int slot = atomicAdd(&node_order[p], 1);
  if (slot < MAXDEG) bucket[(size_t)p * MAXDEG + slot] = e;
}

__global__ void k_rank(const int* __restrict__ par, int E, int N,
                       const int* __restrict__ node_order, const int* __restrict__ bucket,
                       int* __restrict__ edgeCnt, int* __restrict__ edgeList) {
  __shared__ int lcnt[MAXIT], lbase[MAXIT];
  const int t = threadIdx.x;
  if (t < MAXIT) lcnt[t] = 0;
  __syncthreads();
  int e = blockIdx.x * blockDim.x + t;
  int r = 0, ls = 0;
  if (e < E) {
    int p = par[e];
    int d = node_order[p]; if (d > MAXDEG) d = MAXDEG;
    int rr = 1;
    for (int j = 0; j < d; ++j) rr += (bucket[(size_t)p * MAXDEG + j] < e) ? 1 : 0;
    if (rr < MAXIT) { r = rr; ls = atomicAdd(&lcnt[rr], 1); }
  }
  __syncthreads();
  if (t < MAXIT && lcnt[t] > 0) lbase[t] = atomicAdd(&edgeCnt[t], lcnt[t]);
  __syncthreads();
  if (r > 0) edgeList[(size_t)r * N + lbase[r] + ls] = e;
}

__global__ void k_nodelist(int N, const int* __restrict__ node_order,
                           int* __restrict__ nodeCnt, int* __restrict__ nodeList) {
  __shared__ int lcnt[MAXIT], lbase[MAXIT];
  const int t = threadIdx.x;
  if (t < MAXIT) lcnt[t] = 0;
  __syncthreads();
  int v = blockIdx.x * blockDim.x + t;
  int n = -1, ls = 0;
  if (v < N) {
    n = node_order[v]; if (n >= MAXIT) n = MAXIT - 1;
    ls = atomicAdd(&lcnt[n], 1);
  }
  __syncthreads();
  if (t < MAXIT && lcnt[t] > 0) lbase[t] = atomicAdd(&nodeCnt[t], lcnt[t]);
  __syncthreads();
  if (n >= 0) nodeList[(size_t)n * N + lbase[n] + ls] = v;
}

// ---------------- x -> bf16 mirror ----------------
__global__ void k_pack_x(const float* __restrict__ x, unsigned short* __restrict__ xb, size_t n8) {
  size_t i = (size_t)blockIdx.x * blockDim.x + threadIdx.x;
  size_t st = (size_t)gridDim.x * blockDim.x;
  for (; i < n8; i += st) {
    const float* p = x + i * 8;
    float4 f0 = *(const float4*)p, f1 = *(const float4*)(p + 4);
    uint4 r;
    r.x = (unsigned)f2bf(f0.x) | ((unsigned)f2bf(f0.y) << 16);
    r.y = (unsigned)f2bf(f0.z) | ((unsigned)f2bf(f0.w) << 16);
    r.z = (unsigned)f2bf(f1.x) | ((unsigned)f2bf(f1.y) << 16);
    r.w = (unsigned)f2bf(f1.z) | ((unsigned)f2bf(f1.w) << 16);
    *(uint4*)(xb + i * 8) = r;
  }
}

// ---------------- weight packs: jc-contiguous fragment-linear B (R11/R12-verified) ----------------
__global__ void k_pack_biou(const float* __restrict__ W, const float* __restrict__ U,
                            unsigned short* __restrict__ Bpk) {
  int i = blockIdx.x * blockDim.x + threadIdx.x;
  if (i >= 16 * 64 * 3 * 64) return;
  int lane = i & 63;
  int q = i >> 6;
  int g = q % 3; q /= 3;
  int s = q & 63;
  int jc = q >> 6;
  int col = jc * 32 + (lane & 31);
  int k0 = s * 16 + (lane >> 5) * 8;
  int rowW = g * 512 + col;
  unsigned short v[8];
#pragma unroll
  for (int j = 0; j < 8; ++j) {
    int kk = k0 + j;
    v[j] = f2bf(kk < 512 ? W[(size_t)rowW * 512 + kk] : U[(size_t)rowW * 512 + kk - 512]);
  }
  *(uint4*)(Bpk + (size_t)i * 8) = *(uint4*)v;
}

__global__ void k_pack_bf(const float* __restrict__ W, const float* __restrict__ U,
                          unsigned short* __restrict__ Bpk) {
  int i = blockIdx.x * blockDim.x + threadIdx.x;
  if (i >= 16 * 64 * 64) return;
  int lane = i & 63;
  int q = i >> 6;
  int s = q & 63;
  int jc = q >> 6;
  int col = jc * 32 + (lane & 31);
  int k0 = s * 16 + (lane >> 5) * 8;
  unsigned short v[8];
#pragma unroll
  for (int j = 0; j < 8; ++j) {
    int kk = k0 + j;
    v[j] = f2bf(kk < 512 ? W[(size_t)col * 512 + kk] : U[(size_t)col * 512 + kk - 512]);
  }
  *(uint4*)(Bpk + (size_t)i * 8) = *(uint4*)v;
}

// ---------------- fused: addfc(n-1) for deg>n-1 parents + hsumb(n) ----------------
__global__ void k_edge_pre(int n, int N, const int* __restrict__ edgeCnt, const int* __restrict__ edgeList,
                           const int* __restrict__ par, const int* __restrict__ chd,
                           const int* __restrict__ node_order,
                           const unsigned short* __restrict__ hb, unsigned short* __restrict__ hsumb,
                           const unsigned short* __restrict__ fc, float* __restrict__ c) {
  const int cntH = edgeCnt[n];
  const int cntA = (n >= 2) ? edgeCnt[n - 1] : 0;
  const size_t totH = (size_t)cntH * 64;
  const size_t total = totH + (size_t)cntA * 64;
  size_t st = (size_t)gridDim.x * blockDim.x;
  for (size_t i = (size_t)blockIdx.x * blockDim.x + threadIdx.x; i < total; i += st) {
    if (i < totH) {
      int slot = (int)(i >> 6), j8 = ((int)i & 63) << 3;
      int e = edgeList[(size_t)n * N + slot];
      int p = par[e], ch = chd[e];
      uint4 hv = *(const uint4*)&hb[(size_t)ch * 512 + j8];
      if (n == 1) {
        *(uint4*)&hsumb[(size_t)p * 512 + j8] = hv;
      } else {
        uint4 hs = *(const uint4*)&hsumb[(size_t)p * 512 + j8];
        *(uint4*)&hsumb[(size_t)p * 512 + j8] = bfadd8(hs, hv);
      }
    } else {
      size_t k = i - totH;
      int slot = (int)(k >> 6), j8 = ((int)k & 63) << 3;
      int e = edgeList[(size_t)(n - 1) * N + slot];
      int p = par[e];
      if (node_order[p] <= n - 1) continue;   // deg==n-1 handled in iou epilogue
      size_t base = (size_t)p * 512 + j8;
      uint4 f8 = *(const uint4*)&fc[base];
      unsigned fw[4] = {f8.x, f8.y, f8.z, f8.w};
      float4 c0 = *(const float4*)&c[base];
      float4 c1 = *(const float4*)&c[base + 4];
      c0.x += bf2f((unsigned short)(fw[0] & 0xFFFFu)); c0.y += bf2f((unsigned short)(fw[0] >> 16));
      c0.z += bf2f((unsigned short)(fw[1] & 0xFFFFu)); c0.w += bf2f((unsigned short)(fw[1] >> 16));
      c1.x += bf2f((unsigned short)(fw[2] & 0xFFFFu)); c1.y += bf2f((unsigned short)(fw[2] >> 16));
      c1.z += bf2f((unsigned short)(fw[3] & 0xFFFFu)); c1.w += bf2f((unsigned short)(fw[3] >> 16));
      *(float4*)&c[base] = c0;
      *(float4*)&c[base + 4] = c1;
    }
  }
}

// ---------------- A-resident MFMA GEMM: R12 structure + global_load_lds staging ----------------
// MODE 0: iou wavefront 0 (K=512: xb; bias W; 32KB LDS)
// MODE 1: iou n>=1      (K=1024: [xb | hsumb]; bias W+U; +fc; writes c,h,hb)
// MODE 2: f GEMM        (K=1024: [xb[par] | hb[chd]]; fc[par]=sigm(acc+b)*c[chd];
//                        2 col streams/wave)
// 256 thr / 4 waves / (256,2): allocator headroom proven (R12: VGPR 100, no spill).
// Staging: async global_load_lds, linear LDS dest (wave-uniform base + lane*16),
// slot->src decode inverts the XOR layout (bijective; read side unchanged).
template<int MODE>
__global__ __launch_bounds__(256, 2)
void k_gemm9(int n, int N, const int* __restrict__ cntArr, const int* __restrict__ list,
             const int* __restrict__ par, const int* __restrict__ chd,
             const unsigned short* __restrict__ xb, const unsigned short* __restrict__ hsrc,
             const unsigned short* __restrict__ Bpk,
             const float* __restrict__ bW, const float* __restrict__ bU,
             float* __restrict__ c, float* __restrict__ h, unsigned short* __restrict__ hb,
             unsigned short* __restrict__ fc) {
  const int cnt = cntArr[n];
  if (cnt == 0) return;
  constexpr int KS    = (MODE == 0) ? 32 : 64;
  constexpr int KC8   = KS * 2;
  constexpr int GATES = (MODE == 2) ? 1 : 3;
  constexpr int NSTR  = (MODE == 2) ? 2 : 1;
  constexpr int NPASS = (MODE == 2) ? 2 : 4;
  constexpr int D     = 4;
  const int rowTiles = (cnt + 31) >> 5;

  __shared__ uint4 lA4[KS * 64];
  __shared__ int ids0[32], ids1[32];
  const int t = threadIdx.x, lane = t & 63, w = t >> 6;

  auto ldA = [&](int s) -> bf16x8 {
    int hk = lane >> 5, rl = lane & 31;
    return *(const bf16x8*)&lA4[s * 64 + hk * 32 + (rl ^ ((2 * s + hk) & 31))];
  };

  for (int tile = blockIdx.x; tile < rowTiles; tile += gridDim.x) {
    __syncthreads();
    if (t < 32) {
      int r = (tile << 5) + t;
      int idx = (r < cnt) ? list[(size_t)n * N + r] : -1;
      if (MODE == 2) { ids0[t] = idx >= 0 ? par[idx] : -1; ids1[t] = idx >= 0 ? chd[idx] : 0; }
      else           { ids0[t] = idx; ids1[t] = 0; }
    }
    __syncthreads();

    // ---- stage A: async DMA; per-lane global src decoded from linear LDS slot ----
    constexpr int ITERS = (32 * KC8) / 256;      // 8 or 16
#pragma unroll
    for (int i = 0; i < ITERS; ++i) {
      int slot = i * 256 + t;
      int s = slot >> 6;                  // wave-uniform
      int hk = (slot >> 5) & 1;
      int kc8 = 2 * s + hk;
      int row = (slot & 31) ^ (kc8 & 31); // invert XOR store layout
      const unsigned short* gp;
      if (MODE == 0 || kc8 < 64) {        // uniform branch (s uniform per wave)
        int id0 = ids0[row];
        gp = xb + (size_t)(id0 < 0 ? 0 : id0) * 512 + (kc8 << 3);
      } else {
        int idh;
        if (MODE == 2) { idh = ids1[row]; }
        else { int id0 = ids0[row]; idh = id0 < 0 ? 0 : id0; }
        gp = hsrc + (size_t)idh * 512 + ((kc8 - 64) << 3);
      }
      gload_lds16(gp, &lA4[i * 256 + (t & ~63)]);   // wave-uniform LDS base
    }
    __syncthreads();                      // drains vmcnt before compute

    for (int p = 0; p < NPASS; ++p) {
      const uint4* bb[NSTR];
#pragma unroll
      for (int str = 0; str < NSTR; ++str) {
        int jc = (MODE == 2) ? (p * 8 + str * 4 + w) : (p * 4 + w);
        bb[str] = (const uint4*)Bpk + (size_t)jc * 64 * GATES * 64 + lane;
      }
      f32x16 acc[NSTR][GATES];
#pragma unroll
      for (int str = 0; str < NSTR; ++str)
#pragma unroll
        for (int g = 0; g < GATES; ++g)
#pragma unroll
          for (int q = 0; q < 16; ++q) acc[str][g][q] = 0.f;

      bf16x8 aP[D];
      uint4 bP[D][NSTR * GATES];
#pragma unroll
      for (int d = 0; d < D; ++d) {
        aP[d] = ldA(d);
#pragma unroll
        for (int str = 0; str < NSTR; ++str)
#pragma unroll
          for (int g = 0; g < GATES; ++g)
            bP[d][str * GATES + g] = bb[str][(size_t)(d * GATES + g) * 64];
      }
      for (int s0 = 0; s0 < KS - D; s0 += D) {
#pragma unroll
        for (int d = 0; d < D; ++d) {
#pragma unroll
          for (int str = 0; str < NSTR; ++str)
#pragma unroll
            for (int g = 0; g < GATES; ++g)
              acc[str][g] = __builtin_amdgcn_mfma_f32_32x32x16_bf16(
                  aP[d], *(bf16x8*)&bP[d][str * GATES + g], acc[str][g], 0, 0, 0);
          aP[d] = ldA(s0 + D + d);
#pragma unroll
          for (int str = 0; str < NSTR; ++str)
#pragma unroll
            for (int g = 0; g < GATES; ++g)
              bP[d][str * GATES + g] = bb[str][(size_t)((s0 + D + d) * GATES + g) * 64];
        }
      }
#pragma unroll
      for (int d = 0; d < D; ++d)
#pragma unroll
        for (int str = 0; str < NSTR; ++str)
#pragma unroll
          for (int g = 0; g < GATES; ++g)
            acc[str][g] = __builtin_amdgcn_mfma_f32_32x32x16_bf16(
                aP[d], *(bf16x8*)&bP[d][str * GATES + g], acc[str][g], 0, 0, 0);

#pragma unroll
      for (int str = 0; str < NSTR; ++str) {
        const int jc = (MODE == 2) ? (p * 8 + str * 4 + w) : (p * 4 + w);
        const int jh = jc * 32 + (lane & 31);
        if (MODE < 2) {
          float bi = bW[jh], bo = bW[512 + jh], bu = bW[1024 + jh];
          if (MODE == 1) { bi += bU[jh]; bo += bU[512 + jh]; bu += bU[1024 + jh]; }
#pragma unroll
          for (int reg = 0; reg < 16; ++reg) {
            int rl = ((lane >> 5) << 2) + (reg & 3) + ((reg >> 2) << 3);
            int node = ids0[rl];
            if (node < 0) continue;
            size_t base = (size_t)node * 512 + jh;
            float iv = acc[str][0][reg] + bi;
            float ov = acc[str][1][reg] + bo;
            float uv = acc[str][2][reg] + bu;
            float fcv = (MODE == 1) ? bf2f(fc[base]) : 0.f;
            float cn = sigm(iv) * tfast(uv) + fcv;
            c[base] = cn;
            float hv = sigm(ov) * tfast(cn);
            h[base] = hv;
            hb[base] = f2bf(hv);
          }
        } else {
          float bfv = bW[jh] + bU[jh];
#pragma unroll
          for (int reg = 0; reg < 16; ++reg) {
            int rl = ((lane >> 5) << 2) + (reg & 3) + ((reg >> 2) << 3);
            int pe = ids0[rl];
            if (pe < 0) continue;
            int ce = ids1[rl];
            float fv = sigm(acc[str][0][reg] + bfv);
            fc[(size_t)pe * 512 + jh] = f2bf(fv * c[(size_t)ce * 512 + jh]);
          }
        }
      }
    }
  }
}

// ---------------- driver (exact R12) ----------------
static void run_all(const float* x, const int* par, const int* chd,
                    const float* Wiou, const float* bWiou, const float* Uiou, const float* bUiou,
                    const float* Wf, const float* bWf, const float* Uf, const float* bUf,
                    float* h, int N, int E, void* d_ws, hipStream_t stream) {
  const size_t NV = (size_t)N * 512;
  char* cur = (char*)d_ws;
  auto take = [&](size_t bytes) -> char* {
    char* r = cur; cur += (bytes + 255) & ~(size_t)255; return r;
  };
  float* c             = (float*)take(NV * 4);
  unsigned short* hb   = (unsigned short*)take(NV * 2);
  unsigned short* hsumb= (unsigned short*)take(NV * 2);
  unsigned short* xb   = (unsigned short*)take(NV * 2);
  unsigned short* fc   = (unsigned short*)take(NV * 2);
  unsigned short* BpkI = (unsigned short*)take((size_t)16 * 64 * 3 * 64 * 8 * 2);
  unsigned short* BpkF = (unsigned short*)take((size_t)16 * 64 * 64 * 8 * 2);
  int* node_order      = (int*)take((size_t)N * 4);
  int* nodeCnt         = (int*)take(MAXIT * 4);
  int* edgeCnt         = (int*)take(MAXIT * 4);
  int* bucket          = (int*)take((size_t)N * MAXDEG * 4);
  int* nodeList        = (int*)take((size_t)MAXIT * N * 4);
  int* edgeList        = (int*)take((size_t)MAXIT * N * 4);

  kzero16<<<2048, 256, 0, stream>>>((uint4*)c, NV * 4 / 16);
  kzero16<<<2048, 256, 0, stream>>>((uint4*)hb, NV * 2 / 16);
  kzeroi<<<(N + 255) / 256, 256, 0, stream>>>(node_order, N);
  kzeroi<<<1, 64, 0, stream>>>(nodeCnt, MAXIT);
  kzeroi<<<1, 64, 0, stream>>>(edgeCnt, MAXIT);

  k_pack_x<<<2048, 256, 0, stream>>>(x, xb, NV / 8);
  k_pack_biou<<<(16 * 64 * 3 * 64 + 255) / 256, 256, 0, stream>>>(Wiou, Uiou, BpkI);
  k_pack_bf<<<(16 * 64 * 64 + 255) / 256, 256, 0, stream>>>(Wf, Uf, BpkF);

  k_histo<<<(E + 255) / 256, 256, 0, stream>>>(par, E, node_order, bucket);
  k_rank<<<(E + 255) / 256, 256, 0, stream>>>(par, E, N, node_order, bucket, edgeCnt, edgeList);
  k_nodelist<<<(N + 255) / 256, 256, 0, stream>>>(N, node_order, nodeCnt, nodeList);

  {
    int g = imin(4096, (N + 31) >> 5);
    k_gemm9<0><<<g, 256, 0, stream>>>(0, N, nodeCnt, nodeList, par, chd,
                                      xb, hsumb, BpkI, bWiou, bUiou, c, h, hb, fc);
  }
  for (int n = 1; n < MAXIT; ++n) {
    int boundE = E / n;
    int boundN = imin(N, boundE);
    int boundA = (n >= 2) ? (E / (n - 1)) : 0;
    int gE = imin(2048, (int)(((size_t)(boundE + boundA) * 64 + 255) / 256));
    int gF = imin(4096, (boundE + 31) >> 5);
    int gI = imin(4096, (boundN + 31) >> 5);
    k_edge_pre<<<gE, 256, 0, stream>>>(n, N, edgeCnt, edgeList, par, chd, node_order,
                                       hb, hsumb, fc, c);
    k_gemm9<2><<<gF, 256, 0, stream>>>(n, N, edgeCnt, edgeList, par, chd,
                                       xb, hb, BpkF, bWf, bUf, c, h, hb, fc);
    k_gemm9<1><<<gI, 256, 0, stream>>>(n, N, nodeCnt, nodeList, par, chd,
                                       xb, hsumb, BpkI, bWiou, bUiou, c, h, hb, fc);
  }
}

extern "C" void kernel_launch(void* const* d_in, const int* in_sizes, int n_in,
                              void* d_out, int out_size, void* d_ws, size_t ws_size,
                              hipStream_t stream) {
  (void)n_in; (void)out_size;
  const float* x     = (const float*)d_in[0];
  const int*   ei    = (const int*)d_in[1];
  const float* Wiou  = (const float*)d_in[4];
  const float* bWiou = (const float*)d_in[5];
  const float* Uiou  = (const float*)d_in[6];
  const float* bUiou = (const float*)d_in[7];
  const float* Wf    = (const float*)d_in[8];
  const float* bWf   = (const float*)d_in[9];
  const float* Uf    = (const float*)d_in[10];
  const float* bUf   = (const float*)d_in[11];
  const int N = in_sizes[0] / 512;
  const int E = in_sizes[1] / 2;
  const int* par = ei;
  const int* chd = ei + E;
  float* h = (float*)d_out;

  const size_t NV = (size_t)N * 512;
  const size_t need = NV * 12 + (size_t)8 * 1024 * 1024 +
                      ((size_t)N * (1 + MAXDEG + 2 * MAXIT) + 512) * 4;

  if (ws_size >= need) {
    run_all(x, par, chd, Wiou, bWiou, Uiou, bUiou, Wf, bWf, Uf, bUf,
            h, N, E, d_ws, stream);
  } else {
    kfill<<<2048, 256, 0, stream>>>(h, NV, 1.0e6f);  // diagnostic sentinel: ws too small
  }
}

// Round 19
// 2535.481 us; speedup vs baseline: 1.2211x; 1.0072x over previous
//
#include <hip/hip_runtime.h>
#include <math.h>

#define MAXIT 16      // wavefronts 0..15 (max in-degree ~13 for Poisson(2))
#define MAXDEG 16     // per-parent bucket capacity for ranking

typedef __attribute__((ext_vector_type(8))) short bf16x8;
typedef __attribute__((ext_vector_type(16))) float f32x16;

static inline int imin(int a, int b) { return a < b ? a : b; }

__device__ __forceinline__ float sigm(float v) { return 1.0f / (1.0f + __expf(-v)); }
__device__ __forceinline__ float tfast(float v) {
  float vc = fminf(fmaxf(v, -20.0f), 20.0f);
  float t = __expf(2.0f * vc);
  return (t - 1.0f) / (t + 1.0f);
}
__device__ __forceinline__ unsigned short f2bf(float f) {
  unsigned int u = __float_as_uint(f);
  u += 0x7FFFu + ((u >> 16) & 1u);
  return (unsigned short)(u >> 16);
}
__device__ __forceinline__ float bf2f(unsigned short s) {
  return __uint_as_float(((unsigned int)s) << 16);
}
__device__ __forceinline__ unsigned bfadd2(unsigned x, unsigned y) {
  float sl = bf2f((unsigned short)(x & 0xFFFFu)) + bf2f((unsigned short)(y & 0xFFFFu));
  float sh = bf2f((unsigned short)(x >> 16)) + bf2f((unsigned short)(y >> 16));
  return (unsigned)f2bf(sl) | ((unsigned)f2bf(sh) << 16);
}
__device__ __forceinline__ uint4 bfadd8(uint4 a, uint4 b) {
  return make_uint4(bfadd2(a.x, b.x), bfadd2(a.y, b.y), bfadd2(a.z, b.z), bfadd2(a.w, b.w));
}

// async global->LDS, 16B per lane; lds base must be wave-uniform (HW adds lane*16)
__device__ __forceinline__ void gload_lds16(const unsigned short* g, void* l) {
  __builtin_amdgcn_global_load_lds(
      (const __attribute__((address_space(1))) unsigned int*)g,
      (__attribute__((address_space(3))) unsigned int*)l, 16, 0, 0);
}

// ---------------- fills ----------------
__global__ void kzero16(uint4* p, size_t n) {
  size_t i = (size_t)blockIdx.x * blockDim.x + threadIdx.x;
  size_t st = (size_t)gridDim.x * blockDim.x;
  uint4 z = make_uint4(0u, 0u, 0u, 0u);
  for (; i < n; i += st) p[i] = z;
}
__global__ void kzeroi(int* p, int n) {
  int i = blockIdx.x * blockDim.x + threadIdx.x;
  if (i < n) p[i] = 0;
}
__global__ void kfill(float* p, size_t n, float v) {
  size_t i = (size_t)blockIdx.x * blockDim.x + threadIdx.x;
  size_t st = (size_t)gridDim.x * blockDim.x;
  for (; i < n; i += st) p[i] = v;
}

// ---------------- graph precompute ----------------
__global__ void k_histo(const int* __restrict__ par, int E,
                        int* __restrict__ node_order, int* __restrict__ bucket) {
  int e = blockIdx.x * blockDim.x + threadIdx.x;
  if (e >= E) return;
  int p = par[e];
  int slot = atomicAdd(&node_order[p], 1);
  if (slot < MAXDEG) bucket[(size_t)p * MAXDEG + slot] = e;
}

__global__ void k_rank(const int* __restrict__ par, int E, int N,
                       const int* __restrict__ node_order, const int* __restrict__ bucket,
                       int* __restrict__ edgeCnt, int* __restrict__ edgeList) {
  __shared__ int lcnt[MAXIT], lbase[MAXIT];
  const int t = threadIdx.x;
  if (t < MAXIT) lcnt[t] = 0;
  __syncthreads();
  int e = blockIdx.x * blockDim.x + t;
  int r = 0, ls = 0;
  if (e < E) {
    int p = par[e];
    int d = node_order[p]; if (d > MAXDEG) d = MAXDEG;
    int rr = 1;
    for (int j = 0; j < d; ++j) rr += (bucket[(size_t)p * MAXDEG + j] < e) ? 1 : 0;
    if (rr < MAXIT) { r = rr; ls = atomicAdd(&lcnt[rr], 1); }
  }
  __syncthreads();
  if (t < MAXIT && lcnt[t] > 0) lbase[t] = atomicAdd(&edgeCnt[t], lcnt[t]);
  __syncthreads();
  if (r > 0) edgeList[(size_t)r * N + lbase[r] + ls] = e;
}

__global__ void k_nodelist(int N, const int* __restrict__ node_order,
                           int* __restrict__ nodeCnt, int* __restrict__ nodeList) {
  __shared__ int lcnt[MAXIT], lbase[MAXIT];
  const int t = threadIdx.x;
  if (t < MAXIT) lcnt[t] = 0;
  __syncthreads();
  int v = blockIdx.x * blockDim.x + t;
  int n = -1, ls = 0;
  if (v < N) {
    n = node_order[v]; if (n >= MAXIT) n = MAXIT - 1;
    ls = atomicAdd(&lcnt[n], 1);
  }
  __syncthreads();
  if (t < MAXIT && lcnt[t] > 0) lbase[t] = atomicAdd(&nodeCnt[t], lcnt[t]);
  __syncthreads();
  if (n >= 0) nodeList[(size_t)n * N + lbase[n] + ls] = v;
}

// ---------------- x -> bf16 mirror ----------------
__global__ void k_pack_x(const float* __restrict__ x, unsigned short* __restrict__ xb, size_t n8) {
  size_t i = (size_t)blockIdx.x * blockDim.x + threadIdx.x;
  size_t st = (size_t)gridDim.x * blockDim.x;
  for (; i < n8; i += st) {
    const float* p = x + i * 8;
    float4 f0 = *(const float4*)p, f1 = *(const float4*)(p + 4);
    uint4 r;
    r.x = (unsigned)f2bf(f0.x) | ((unsigned)f2bf(f0.y) << 16);
    r.y = (unsigned)f2bf(f0.z) | ((unsigned)f2bf(f0.w) << 16);
    r.z = (unsigned)f2bf(f1.x) | ((unsigned)f2bf(f1.y) << 16);
    r.w = (unsigned)f2bf(f1.z) | ((unsigned)f2bf(f1.w) << 16);
    *(uint4*)(xb + i * 8) = r;
  }
}

// ---------------- weight packs: jc-contiguous fragment-linear B (R11/R12-verified) ----------------
__global__ void k_pack_biou(const float* __restrict__ W, const float* __restrict__ U,
                            unsigned short* __restrict__ Bpk) {
  int i = blockIdx.x * blockDim.x + threadIdx.x;
  if (i >= 16 * 64 * 3 * 64) return;
  int lane = i & 63;
  int q = i >> 6;
  int g = q % 3; q /= 3;
  int s = q & 63;
  int jc = q >> 6;
  int col = jc * 32 + (lane & 31);
  int k0 = s * 16 + (lane >> 5) * 8;
  int rowW = g * 512 + col;
  unsigned short v[8];
#pragma unroll
  for (int j = 0; j < 8; ++j) {
    int kk = k0 + j;
    v[j] = f2bf(kk < 512 ? W[(size_t)rowW * 512 + kk] : U[(size_t)rowW * 512 + kk - 512]);
  }
  *(uint4*)(Bpk + (size_t)i * 8) = *(uint4*)v;
}

__global__ void k_pack_bf(const float* __restrict__ W, const float* __restrict__ U,
                          unsigned short* __restrict__ Bpk) {
  int i = blockIdx.x * blockDim.x + threadIdx.x;
  if (i >= 16 * 64 * 64) return;
  int lane = i & 63;
  int q = i >> 6;
  int s = q & 63;
  int jc = q >> 6;
  int col = jc * 32 + (lane & 31);
  int k0 = s * 16 + (lane >> 5) * 8;
  unsigned short v[8];
#pragma unroll
  for (int j = 0; j < 8; ++j) {
    int kk = k0 + j;
    v[j] = f2bf(kk < 512 ? W[(size_t)col * 512 + kk] : U[(size_t)col * 512 + kk - 512]);
  }
  *(uint4*)(Bpk + (size_t)i * 8) = *(uint4*)v;
}

// ---------------- fused: addfc(n-1) for deg>n-1 parents + hsumb(n) ----------------
__global__ void k_edge_pre(int n, int N, const int* __restrict__ edgeCnt, const int* __restrict__ edgeList,
                           const int* __restrict__ par, const int* __restrict__ chd,
                           const int* __restrict__ node_order,
                           const unsigned short* __restrict__ hb, unsigned short* __restrict__ hsumb,
                           const unsigned short* __restrict__ fc, float* __restrict__ c) {
  const int cntH = edgeCnt[n];
  const int cntA = (n >= 2) ? edgeCnt[n - 1] : 0;
  const size_t totH = (size_t)cntH * 64;
  const size_t total = totH + (size_t)cntA * 64;
  size_t st = (size_t)gridDim.x * blockDim.x;
  for (size_t i = (size_t)blockIdx.x * blockDim.x + threadIdx.x; i < total; i += st) {
    if (i < totH) {
      int slot = (int)(i >> 6), j8 = ((int)i & 63) << 3;
      int e = edgeList[(size_t)n * N + slot];
      int p = par[e], ch = chd[e];
      uint4 hv = *(const uint4*)&hb[(size_t)ch * 512 + j8];
      if (n == 1) {
        *(uint4*)&hsumb[(size_t)p * 512 + j8] = hv;
      } else {
        uint4 hs = *(const uint4*)&hsumb[(size_t)p * 512 + j8];
        *(uint4*)&hsumb[(size_t)p * 512 + j8] = bfadd8(hs, hv);
      }
    } else {
      size_t k = i - totH;
      int slot = (int)(k >> 6), j8 = ((int)k & 63) << 3;
      int e = edgeList[(size_t)(n - 1) * N + slot];
      int p = par[e];
      if (node_order[p] <= n - 1) continue;   // deg==n-1 handled in iou epilogue
      size_t base = (size_t)p * 512 + j8;
      uint4 f8 = *(const uint4*)&fc[base];
      unsigned fw[4] = {f8.x, f8.y, f8.z, f8.w};
      float4 c0 = *(const float4*)&c[base];
      float4 c1 = *(const float4*)&c[base + 4];
      c0.x += bf2f((unsigned short)(fw[0] & 0xFFFFu)); c0.y += bf2f((unsigned short)(fw[0] >> 16));
      c0.z += bf2f((unsigned short)(fw[1] & 0xFFFFu)); c0.w += bf2f((unsigned short)(fw[1] >> 16));
      c1.x += bf2f((unsigned short)(fw[2] & 0xFFFFu)); c1.y += bf2f((unsigned short)(fw[2] >> 16));
      c1.z += bf2f((unsigned short)(fw[3] & 0xFFFFu)); c1.w += bf2f((unsigned short)(fw[3] >> 16));
      *(float4*)&c[base] = c0;
      *(float4*)&c[base + 4] = c1;
    }
  }
}

// ---------------- A-resident MFMA GEMM: R18 + s_setprio around MFMA chunks ----------------
// MODE 0: iou wavefront 0 (K=512: xb; bias W; 32KB LDS)
// MODE 1: iou n>=1      (K=1024: [xb | hsumb]; bias W+U; +fc; writes c,h,hb)
// MODE 2: f GEMM        (K=1024: [xb[par] | hb[chd]]; fc[par]=sigm(acc+b)*c[chd])
// 256 thr / 4 waves / (256,2); DMA staging (R18-verified, VGPR 112 no-spill);
// setprio(1) during compute passes biases CU scheduler vs co-resident block's DMA.
template<int MODE>
__global__ __launch_bounds__(256, 2)
void k_gemm9(int n, int N, const int* __restrict__ cntArr, const int* __restrict__ list,
             const int* __restrict__ par, const int* __restrict__ chd,
             const unsigned short* __restrict__ xb, const unsigned short* __restrict__ hsrc,
             const unsigned short* __restrict__ Bpk,
             const float* __restrict__ bW, const float* __restrict__ bU,
             float* __restrict__ c, float* __restrict__ h, unsigned short* __restrict__ hb,
             unsigned short* __restrict__ fc) {
  const int cnt = cntArr[n];
  if (cnt == 0) return;
  constexpr int KS    = (MODE == 0) ? 32 : 64;
  constexpr int KC8   = KS * 2;
  constexpr int GATES = (MODE == 2) ? 1 : 3;
  constexpr int NSTR  = (MODE == 2) ? 2 : 1;
  constexpr int NPASS = (MODE == 2) ? 2 : 4;
  constexpr int D     = 4;
  const int rowTiles = (cnt + 31) >> 5;

  __shared__ uint4 lA4[KS * 64];
  __shared__ int ids0[32], ids1[32];
  const int t = threadIdx.x, lane = t & 63, w = t >> 6;

  auto ldA = [&](int s) -> bf16x8 {
    int hk = lane >> 5, rl = lane & 31;
    return *(const bf16x8*)&lA4[s * 64 + hk * 32 + (rl ^ ((2 * s + hk) & 31))];
  };

  for (int tile = blockIdx.x; tile < rowTiles; tile += gridDim.x) {
    __syncthreads();
    if (t < 32) {
      int r = (tile << 5) + t;
      int idx = (r < cnt) ? list[(size_t)n * N + r] : -1;
      if (MODE == 2) { ids0[t] = idx >= 0 ? par[idx] : -1; ids1[t] = idx >= 0 ? chd[idx] : 0; }
      else           { ids0[t] = idx; ids1[t] = 0; }
    }
    __syncthreads();

    // ---- stage A: async DMA; per-lane global src decoded from linear LDS slot ----
    constexpr int ITERS = (32 * KC8) / 256;      // 8 or 16
#pragma unroll
    for (int i = 0; i < ITERS; ++i) {
      int slot = i * 256 + t;
      int s = slot >> 6;                  // wave-uniform
      int hk = (slot >> 5) & 1;
      int kc8 = 2 * s + hk;
      int row = (slot & 31) ^ (kc8 & 31); // invert XOR store layout
      const unsigned short* gp;
      if (MODE == 0 || kc8 < 64) {        // uniform branch (s uniform per wave)
        int id0 = ids0[row];
        gp = xb + (size_t)(id0 < 0 ? 0 : id0) * 512 + (kc8 << 3);
      } else {
        int idh;
        if (MODE == 2) { idh = ids1[row]; }
        else { int id0 = ids0[row]; idh = id0 < 0 ? 0 : id0; }
        gp = hsrc + (size_t)idh * 512 + ((kc8 - 64) << 3);
      }
      gload_lds16(gp, &lA4[i * 256 + (t & ~63)]);   // wave-uniform LDS base
    }
    __syncthreads();                      // drains vmcnt before compute

    for (int p = 0; p < NPASS; ++p) {
      const uint4* bb[NSTR];
#pragma unroll
      for (int str = 0; str < NSTR; ++str) {
        int jc = (MODE == 2) ? (p * 8 + str * 4 + w) : (p * 4 + w);
        bb[str] = (const uint4*)Bpk + (size_t)jc * 64 * GATES * 64 + lane;
      }
      f32x16 acc[NSTR][GATES];
#pragma unroll
      for (int str = 0; str < NSTR; ++str)
#pragma unroll
        for (int g = 0; g < GATES; ++g)
#pragma unroll
          for (int q = 0; q < 16; ++q) acc[str][g][q] = 0.f;

      bf16x8 aP[D];
      uint4 bP[D][NSTR * GATES];
#pragma unroll
      for (int d = 0; d < D; ++d) {
        aP[d] = ldA(d);
#pragma unroll
        for (int str = 0; str < NSTR; ++str)
#pragma unroll
          for (int g = 0; g < GATES; ++g)
            bP[d][str * GATES + g] = bb[str][(size_t)(d * GATES + g) * 64];
      }
      __builtin_amdgcn_s_setprio(1);      // favor compute-phase wave on this SIMD
      for (int s0 = 0; s0 < KS - D; s0 += D) {
#pragma unroll
        for (int d = 0; d < D; ++d) {
#pragma unroll
          for (int str = 0; str < NSTR; ++str)
#pragma unroll
            for (int g = 0; g < GATES; ++g)
              acc[str][g] = __builtin_amdgcn_mfma_f32_32x32x16_bf16(
                  aP[d], *(bf16x8*)&bP[d][str * GATES + g], acc[str][g], 0, 0, 0);
          aP[d] = ldA(s0 + D + d);
#pragma unroll
          for (int str = 0; str < NSTR; ++str)
#pragma unroll
            for (int g = 0; g < GATES; ++g)
              bP[d][str * GATES + g] = bb[str][(size_t)((s0 + D + d) * GATES + g) * 64];
        }
      }
#pragma unroll
      for (int d = 0; d < D; ++d)
#pragma unroll
        for (int str = 0; str < NSTR; ++str)
#pragma unroll
          for (int g = 0; g < GATES; ++g)
            acc[str][g] = __builtin_amdgcn_mfma_f32_32x32x16_bf16(
                aP[d], *(bf16x8*)&bP[d][str * GATES + g], acc[str][g], 0, 0, 0);
      __builtin_amdgcn_s_setprio(0);

#pragma unroll
      for (int str = 0; str < NSTR; ++str) {
        const int jc = (MODE == 2) ? (p * 8 + str * 4 + w) : (p * 4 + w);
        const int jh = jc * 32 + (lane & 31);
        if (MODE < 2) {
          float bi = bW[jh], bo = bW[512 + jh], bu = bW[1024 + jh];
          if (MODE == 1) { bi += bU[jh]; bo += bU[512 + jh]; bu += bU[1024 + jh]; }
#pragma unroll
          for (int reg = 0; reg < 16; ++reg) {
            int rl = ((lane >> 5) << 2) + (reg & 3) + ((reg >> 2) << 3);
            int node = ids0[rl];
            if (node < 0) continue;
            size_t base = (size_t)node * 512 + jh;
            float iv = acc[str][0][reg] + bi;
            float ov = acc[str][1][reg] + bo;
            float uv = acc[str][2][reg] + bu;
            float fcv = (MODE == 1) ? bf2f(fc[base]) : 0.f;
            float cn = sigm(iv) * tfast(uv) + fcv;
            c[base] = cn;
            float hv = sigm(ov) * tfast(cn);
            h[base] = hv;
            hb[base] = f2bf(hv);
          }
        } else {
          float bfv = bW[jh] + bU[jh];
#pragma unroll
          for (int reg = 0; reg < 16; ++reg) {
            int rl = ((lane >> 5) << 2) + (reg & 3) + ((reg >> 2) << 3);
            int pe = ids0[rl];
            if (pe < 0) continue;
            int ce = ids1[rl];
            float fv = sigm(acc[str][0][reg] + bfv);
            fc[(size_t)pe * 512 + jh] = f2bf(fv * c[(size_t)ce * 512 + jh]);
          }
        }
      }
    }
  }
}

// ---------------- driver (exact R18) ----------------
static void run_all(const float* x, const int* par, const int* chd,
                    const float* Wiou, const float* bWiou, const float* Uiou, const float* bUiou,
                    const float* Wf, const float* bWf, const float* Uf, const float* bUf,
                    float* h, int N, int E, void* d_ws, hipStream_t stream) {
  const size_t NV = (size_t)N * 512;
  char* cur = (char*)d_ws;
  auto take = [&](size_t bytes) -> char* {
    char* r = cur; cur += (bytes + 255) & ~(size_t)255; return r;
  };
  float* c             = (float*)take(NV * 4);
  unsigned short* hb   = (unsigned short*)take(NV * 2);
  unsigned short* hsumb= (unsigned short*)take(NV * 2);
  unsigned short* xb   = (unsigned short*)take(NV * 2);
  unsigned short* fc   = (unsigned short*)take(NV * 2);
  unsigned short* BpkI = (unsigned short*)take((size_t)16 * 64 * 3 * 64 * 8 * 2);
  unsigned short* BpkF = (unsigned short*)take((size_t)16 * 64 * 64 * 8 * 2);
  int* node_order      = (int*)take((size_t)N * 4);
  int* nodeCnt         = (int*)take(MAXIT * 4);
  int* edgeCnt         = (int*)take(MAXIT * 4);
  int* bucket          = (int*)take((size_t)N * MAXDEG * 4);
  int* nodeList        = (int*)take((size_t)MAXIT * N * 4);
  int* edgeList        = (int*)take((size_t)MAXIT * N * 4);

  kzero16<<<2048, 256, 0, stream>>>((uint4*)c, NV * 4 / 16);
  kzero16<<<2048, 256, 0, stream>>>((uint4*)hb, NV * 2 / 16);
  kzeroi<<<(N + 255) / 256, 256, 0, stream>>>(node_order, N);
  kzeroi<<<1, 64, 0, stream>>>(nodeCnt, MAXIT);
  kzeroi<<<1, 64, 0, stream>>>(edgeCnt, MAXIT);

  k_pack_x<<<2048, 256, 0, stream>>>(x, xb, NV / 8);
  k_pack_biou<<<(16 * 64 * 3 * 64 + 255) / 256, 256, 0, stream>>>(Wiou, Uiou, BpkI);
  k_pack_bf<<<(16 * 64 * 64 + 255) / 256, 256, 0, stream>>>(Wf, Uf, BpkF);

  k_histo<<<(E + 255) / 256, 256, 0, stream>>>(par, E, node_order, bucket);
  k_rank<<<(E + 255) / 256, 256, 0, stream>>>(par, E, N, node_order, bucket, edgeCnt, edgeList);
  k_nodelist<<<(N + 255) / 256, 256, 0, stream>>>(N, node_order, nodeCnt, nodeList);

  {
    int g = imin(4096, (N + 31) >> 5);
    k_gemm9<0><<<g, 256, 0, stream>>>(0, N, nodeCnt, nodeList, par, chd,
                                      xb, hsumb, BpkI, bWiou, bUiou, c, h, hb, fc);
  }
  for (int n = 1; n < MAXIT; ++n) {
    int boundE = E / n;
    int boundN = imin(N, boundE);
    int boundA = (n >= 2) ? (E / (n - 1)) : 0;
    int gE = imin(2048, (int)(((size_t)(boundE + boundA) * 64 + 255) / 256));
    int gF = imin(4096, (boundE + 31) >> 5);
    int gI = imin(4096, (boundN + 31) >> 5);
    k_edge_pre<<<gE, 256, 0, stream>>>(n, N, edgeCnt, edgeList, par, chd, node_order,
                                       hb, hsumb, fc, c);
    k_gemm9<2><<<gF, 256, 0, stream>>>(n, N, edgeCnt, edgeList, par, chd,
                                       xb, hb, BpkF, bWf, bUf, c, h, hb, fc);
    k_gemm9<1><<<gI, 256, 0, stream>>>(n, N, nodeCnt, nodeList, par, chd,
                                       xb, hsumb, BpkI, bWiou, bUiou, c, h, hb, fc);
  }
}

extern "C" void kernel_launch(void* const* d_in, const int* in_sizes, int n_in,
                              void* d_out, int out_size, void* d_ws, size_t ws_size,
                              hipStream_t stream) {
  (void)n_in; (void)out_size;
  const float* x     = (const float*)d_in[0];
  const int*   ei    = (const int*)d_in[1];
  const float* Wiou  = (const float*)d_in[4];
  const float* bWiou = (const float*)d_in[5];
  const float* Uiou  = (const float*)d_in[6];
  const float* bUiou = (const float*)d_in[7];
  const float* Wf    = (const float*)d_in[8];
  const float* bWf   = (const float*)d_in[9];
  const float* Uf    = (const float*)d_in[10];
  const float* bUf   = (const float*)d_in[11];
  const int N = in_sizes[0] / 512;
  const int E = in_sizes[1] / 2;
  const int* par = ei;
  const int* chd = ei + E;
  float* h = (float*)d_out;

  const size_t NV = (size_t)N * 512;
  const size_t need = NV * 12 + (size_t)8 * 1024 * 1024 +
                      ((size_t)N * (1 + MAXDEG + 2 * MAXIT) + 512) * 4;

  if (ws_size >= need) {
    run_all(x, par, chd, Wiou, bWiou, Uiou, bUiou, Wf, bWf, Uf, bUf,
            h, N, E, d_ws, stream);
  } else {
    kfill<<<2048, 256, 0, stream>>>(h, NV, 1.0e6f);  // diagnostic sentinel: ws too small
  }
}

// Round 20
// 2524.685 us; speedup vs baseline: 1.2264x; 1.0043x over previous
//
#include <hip/hip_runtime.h>
#include <math.h>

#define MAXIT 16      // wavefronts 0..15 (max in-degree ~13 for Poisson(2))
#define MAXDEG 16     // per-parent bucket capacity for ranking

typedef __attribute__((ext_vector_type(8))) short bf16x8;
typedef __attribute__((ext_vector_type(16))) float f32x16;

static inline int imin(int a, int b) { return a < b ? a : b; }

__device__ __forceinline__ float sigm(float v) { return 1.0f / (1.0f + __expf(-v)); }
__device__ __forceinline__ float tfast(float v) {
  float vc = fminf(fmaxf(v, -20.0f), 20.0f);
  float t = __expf(2.0f * vc);
  return (t - 1.0f) / (t + 1.0f);
}
__device__ __forceinline__ unsigned short f2bf(float f) {
  unsigned int u = __float_as_uint(f);
  u += 0x7FFFu + ((u >> 16) & 1u);
  return (unsigned short)(u >> 16);
}
__device__ __forceinline__ float bf2f(unsigned short s) {
  return __uint_as_float(((unsigned int)s) << 16);
}
__device__ __forceinline__ unsigned bfadd2(unsigned x, unsigned y) {
  float sl = bf2f((unsigned short)(x & 0xFFFFu)) + bf2f((unsigned short)(y & 0xFFFFu));
  float sh = bf2f((unsigned short)(x >> 16)) + bf2f((unsigned short)(y >> 16));
  return (unsigned)f2bf(sl) | ((unsigned)f2bf(sh) << 16);
}
__device__ __forceinline__ uint4 bfadd8(uint4 a, uint4 b) {
  return make_uint4(bfadd2(a.x, b.x), bfadd2(a.y, b.y), bfadd2(a.z, b.z), bfadd2(a.w, b.w));
}

// async global->LDS, 16B per lane; lds base must be wave-uniform (HW adds lane*16)
__device__ __forceinline__ void gload_lds16(const unsigned short* g, void* l) {
  __builtin_amdgcn_global_load_lds(
      (const __attribute__((address_space(1))) unsigned int*)g,
      (__attribute__((address_space(3))) unsigned int*)l, 16, 0, 0);
}

// ---------------- fills ----------------
__global__ void kzero16(uint4* p, size_t n) {
  size_t i = (size_t)blockIdx.x * blockDim.x + threadIdx.x;
  size_t st = (size_t)gridDim.x * blockDim.x;
  uint4 z = make_uint4(0u, 0u, 0u, 0u);
  for (; i < n; i += st) p[i] = z;
}
__global__ void kzeroi(int* p, int n) {
  int i = blockIdx.x * blockDim.x + threadIdx.x;
  if (i < n) p[i] = 0;
}
__global__ void kfill(float* p, size_t n, float v) {
  size_t i = (size_t)blockIdx.x * blockDim.x + threadIdx.x;
  size_t st = (size_t)gridDim.x * blockDim.x;
  for (; i < n; i += st) p[i] = v;
}

// ---------------- graph precompute ----------------
__global__ void k_histo(const int* __restrict__ par, int E,
                        int* __restrict__ node_order, int* __restrict__ bucket) {
  int e = blockIdx.x * blockDim.x + threadIdx.x;
  if (e >= E) return;
  int p = par[e];
  int slot = atomicAdd(&node_order[p], 1);
  if (slot < MAXDEG) bucket[(size_t)p * MAXDEG + slot] = e;
}

__global__ void k_rank(const int* __restrict__ par, int E, int N,
                       const int* __restrict__ node_order, const int* __restrict__ bucket,
                       int* __restrict__ edgeCnt, int* __restrict__ edgeList) {
  __shared__ int lcnt[MAXIT], lbase[MAXIT];
  const int t = threadIdx.x;
  if (t < MAXIT) lcnt[t] = 0;
  __syncthreads();
  int e = blockIdx.x * blockDim.x + t;
  int r = 0, ls = 0;
  if (e < E) {
    int p = par[e];
    int d = node_order[p]; if (d > MAXDEG) d = MAXDEG;
    int rr = 1;
    for (int j = 0; j < d; ++j) rr += (bucket[(size_t)p * MAXDEG + j] < e) ? 1 : 0;
    if (rr < MAXIT) { r = rr; ls = atomicAdd(&lcnt[rr], 1); }
  }
  __syncthreads();
  if (t < MAXIT && lcnt[t] > 0) lbase[t] = atomicAdd(&edgeCnt[t], lcnt[t]);
  __syncthreads();
  if (r > 0) edgeList[(size_t)r * N + lbase[r] + ls] = e;
}

__global__ void k_nodelist(int N, const int* __restrict__ node_order,
                           int* __restrict__ nodeCnt, int* __restrict__ nodeList) {
  __shared__ int lcnt[MAXIT], lbase[MAXIT];
  const int t = threadIdx.x;
  if (t < MAXIT) lcnt[t] = 0;
  __syncthreads();
  int v = blockIdx.x * blockDim.x + t;
  int n = -1, ls = 0;
  if (v < N) {
    n = node_order[v]; if (n >= MAXIT) n = MAXIT - 1;
    ls = atomicAdd(&lcnt[n], 1);
  }
  __syncthreads();
  if (t < MAXIT && lcnt[t] > 0) lbase[t] = atomicAdd(&nodeCnt[t], lcnt[t]);
  __syncthreads();
  if (n >= 0) nodeList[(size_t)n * N + lbase[n] + ls] = v;
}

// ---------------- x -> bf16 mirror ----------------
__global__ void k_pack_x(const float* __restrict__ x, unsigned short* __restrict__ xb, size_t n8) {
  size_t i = (size_t)blockIdx.x * blockDim.x + threadIdx.x;
  size_t st = (size_t)gridDim.x * blockDim.x;
  for (; i < n8; i += st) {
    const float* p = x + i * 8;
    float4 f0 = *(const float4*)p, f1 = *(const float4*)(p + 4);
    uint4 r;
    r.x = (unsigned)f2bf(f0.x) | ((unsigned)f2bf(f0.y) << 16);
    r.y = (unsigned)f2bf(f0.z) | ((unsigned)f2bf(f0.w) << 16);
    r.z = (unsigned)f2bf(f1.x) | ((unsigned)f2bf(f1.y) << 16);
    r.w = (unsigned)f2bf(f1.z) | ((unsigned)f2bf(f1.w) << 16);
    *(uint4*)(xb + i * 8) = r;
  }
}

// ---------------- weight packs: jc-contiguous fragment-linear B (R11/R12-verified) ----------------
__global__ void k_pack_biou(const float* __restrict__ W, const float* __restrict__ U,
                            unsigned short* __restrict__ Bpk) {
  int i = blockIdx.x * blockDim.x + threadIdx.x;
  if (i >= 16 * 64 * 3 * 64) return;
  int lane = i & 63;
  int q = i >> 6;
  int g = q % 3; q /= 3;
  int s = q & 63;
  int jc = q >> 6;
  int col = jc * 32 + (lane & 31);
  int k0 = s * 16 + (lane >> 5) * 8;
  int rowW = g * 512 + col;
  unsigned short v[8];
#pragma unroll
  for (int j = 0; j < 8; ++j) {
    int kk = k0 + j;
    v[j] = f2bf(kk < 512 ? W[(size_t)rowW * 512 + kk] : U[(size_t)rowW * 512 + kk - 512]);
  }
  *(uint4*)(Bpk + (size_t)i * 8) = *(uint4*)v;
}

__global__ void k_pack_bf(const float* __restrict__ W, const float* __restrict__ U,
                          unsigned short* __restrict__ Bpk) {
  int i = blockIdx.x * blockDim.x + threadIdx.x;
  if (i >= 16 * 64 * 64) return;
  int lane = i & 63;
  int q = i >> 6;
  int s = q & 63;
  int jc = q >> 6;
  int col = jc * 32 + (lane & 31);
  int k0 = s * 16 + (lane >> 5) * 8;
  unsigned short v[8];
#pragma unroll
  for (int j = 0; j < 8; ++j) {
    int kk = k0 + j;
    v[j] = f2bf(kk < 512 ? W[(size_t)col * 512 + kk] : U[(size_t)col * 512 + kk - 512]);
  }
  *(uint4*)(Bpk + (size_t)i * 8) = *(uint4*)v;
}

// ---------------- fused: addfc(n-1) for deg>n-1 parents + hsumb(n) ----------------
__global__ void k_edge_pre(int n, int N, const int* __restrict__ edgeCnt, const int* __restrict__ edgeList,
                           const int* __restrict__ par, const int* __restrict__ chd,
                           const int* __restrict__ node_order,
                           const unsigned short* __restrict__ hb, unsigned short* __restrict__ hsumb,
                           const unsigned short* __restrict__ fc, float* __restrict__ c) {
  const int cntH = edgeCnt[n];
  const int cntA = (n >= 2) ? edgeCnt[n - 1] : 0;
  const size_t totH = (size_t)cntH * 64;
  const size_t total = totH + (size_t)cntA * 64;
  size_t st = (size_t)gridDim.x * blockDim.x;
  for (size_t i = (size_t)blockIdx.x * blockDim.x + threadIdx.x; i < total; i += st) {
    if (i < totH) {
      int slot = (int)(i >> 6), j8 = ((int)i & 63) << 3;
      int e = edgeList[(size_t)n * N + slot];
      int p = par[e], ch = chd[e];
      uint4 hv = *(const uint4*)&hb[(size_t)ch * 512 + j8];
      if (n == 1) {
        *(uint4*)&hsumb[(size_t)p * 512 + j8] = hv;
      } else {
        uint4 hs = *(const uint4*)&hsumb[(size_t)p * 512 + j8];
        *(uint4*)&hsumb[(size_t)p * 512 + j8] = bfadd8(hs, hv);
      }
    } else {
      size_t k = i - totH;
      int slot = (int)(k >> 6), j8 = ((int)k & 63) << 3;
      int e = edgeList[(size_t)(n - 1) * N + slot];
      int p = par[e];
      if (node_order[p] <= n - 1) continue;   // deg==n-1 handled in iou epilogue
      size_t base = (size_t)p * 512 + j8;
      uint4 f8 = *(const uint4*)&fc[base];
      unsigned fw[4] = {f8.x, f8.y, f8.z, f8.w};
      float4 c0 = *(const float4*)&c[base];
      float4 c1 = *(const float4*)&c[base + 4];
      c0.x += bf2f((unsigned short)(fw[0] & 0xFFFFu)); c0.y += bf2f((unsigned short)(fw[0] >> 16));
      c0.z += bf2f((unsigned short)(fw[1] & 0xFFFFu)); c0.w += bf2f((unsigned short)(fw[1] >> 16));
      c1.x += bf2f((unsigned short)(fw[2] & 0xFFFFu)); c1.y += bf2f((unsigned short)(fw[2] >> 16));
      c1.z += bf2f((unsigned short)(fw[3] & 0xFFFFu)); c1.w += bf2f((unsigned short)(fw[3] >> 16));
      *(float4*)&c[base] = c0;
      *(float4*)&c[base + 4] = c1;
    }
  }
}

// ---------------- A-resident MFMA GEMM: coalesced DMA staging (row-major LDS, kc8-XOR) ----------------
// MODE 0: iou wavefront 0 (K=512: xb; bias W; 32KB LDS)
// MODE 1: iou n>=1      (K=1024: [xb | hsumb]; bias W+U; +fc; writes c,h,hb)
// MODE 2: f GEMM        (K=1024: [xb[par] | hb[chd]]; fc[par]=sigm(acc+b)*c[chd])
// LDS layout [row][kc8 ^ (row&7)] (uint4 units): linear slot order = row-major ->
// each wave's 64 DMA lanes read one row's contiguous 1KB (permuted-within, coalesced);
// fragment reads spread bank-groups via (lane&7) -> conflict-free. setprio kept (R19).
template<int MODE>
__global__ __launch_bounds__(256, 2)
void k_gemm9(int n, int N, const int* __restrict__ cntArr, const int* __restrict__ list,
             const int* __restrict__ par, const int* __restrict__ chd,
             const unsigned short* __restrict__ xb, const unsigned short* __restrict__ hsrc,
             const unsigned short* __restrict__ Bpk,
             const float* __restrict__ bW, const float* __restrict__ bU,
             float* __restrict__ c, float* __restrict__ h, unsigned short* __restrict__ hb,
             unsigned short* __restrict__ fc) {
  const int cnt = cntArr[n];
  if (cnt == 0) return;
  constexpr int KS    = (MODE == 0) ? 32 : 64;
  constexpr int KC8   = KS * 2;                  // 16B chunks per row
  constexpr int GATES = (MODE == 2) ? 1 : 3;
  constexpr int NSTR  = (MODE == 2) ? 2 : 1;
  constexpr int NPASS = (MODE == 2) ? 2 : 4;
  constexpr int D     = 4;
  const int rowTiles = (cnt + 31) >> 5;

  __shared__ uint4 lA4[32 * KC8];
  __shared__ int ids0[32], ids1[32];
  const int t = threadIdx.x, lane = t & 63, w = t >> 6;

  auto ldA = [&](int s) -> bf16x8 {
    int row = lane & 31;
    int kc8 = 2 * s + (lane >> 5);
    return *(const bf16x8*)&lA4[row * KC8 + (kc8 ^ (row & 7))];
  };

  for (int tile = blockIdx.x; tile < rowTiles; tile += gridDim.x) {
    __syncthreads();
    if (t < 32) {
      int r = (tile << 5) + t;
      int idx = (r < cnt) ? list[(size_t)n * N + r] : -1;
      if (MODE == 2) { ids0[t] = idx >= 0 ? par[idx] : -1; ids1[t] = idx >= 0 ? chd[idx] : 0; }
      else           { ids0[t] = idx; ids1[t] = 0; }
    }
    __syncthreads();

    // ---- stage A: async DMA, coalesced (one row x 64 consecutive chunks per wave) ----
    constexpr int ITERS = (32 * KC8) / 256;      // 8 or 16
#pragma unroll
    for (int i = 0; i < ITERS; ++i) {
      int slot = i * 256 + t;
      int row = slot >> ((MODE == 0) ? 6 : 7);   // wave-uniform
      int col = slot & (KC8 - 1);
      int kc8 = col ^ (row & 7);                 // pre-swizzled global chunk
      const unsigned short* gp;
      if (MODE == 0 || col < 64) {               // wave-uniform branch (bit6 XOR-invariant)
        int id0 = ids0[row];
        gp = xb + (size_t)(id0 < 0 ? 0 : id0) * 512 + (kc8 << 3);
      } else {
        int idh;
        if (MODE == 2) { idh = ids1[row]; }
        else { int id0 = ids0[row]; idh = id0 < 0 ? 0 : id0; }
        gp = hsrc + (size_t)idh * 512 + ((kc8 - 64) << 3);
      }
      gload_lds16(gp, &lA4[i * 256 + (t & ~63)]);   // wave-uniform LDS base, linear dest
    }
    __syncthreads();                      // drains vmcnt before compute

    for (int p = 0; p < NPASS; ++p) {
      const uint4* bb[NSTR];
#pragma unroll
      for (int str = 0; str < NSTR; ++str) {
        int jc = (MODE == 2) ? (p * 8 + str * 4 + w) : (p * 4 + w);
        bb[str] = (const uint4*)Bpk + (size_t)jc * 64 * GATES * 64 + lane;
      }
      f32x16 acc[NSTR][GATES];
#pragma unroll
      for (int str = 0; str < NSTR; ++str)
#pragma unroll
        for (int g = 0; g < GATES; ++g)
#pragma unroll
          for (int q = 0; q < 16; ++q) acc[str][g][q] = 0.f;

      bf16x8 aP[D];
      uint4 bP[D][NSTR * GATES];
#pragma unroll
      for (int d = 0; d < D; ++d) {
        aP[d] = ldA(d);
#pragma unroll
        for (int str = 0; str < NSTR; ++str)
#pragma unroll
          for (int g = 0; g < GATES; ++g)
            bP[d][str * GATES + g] = bb[str][(size_t)(d * GATES + g) * 64];
      }
      __builtin_amdgcn_s_setprio(1);      // favor compute-phase wave on this SIMD
      for (int s0 = 0; s0 < KS - D; s0 += D) {
#pragma unroll
        for (int d = 0; d < D; ++d) {
#pragma unroll
          for (int str = 0; str < NSTR; ++str)
#pragma unroll
            for (int g = 0; g < GATES; ++g)
              acc[str][g] = __builtin_amdgcn_mfma_f32_32x32x16_bf16(
                  aP[d], *(bf16x8*)&bP[d][str * GATES + g], acc[str][g], 0, 0, 0);
          aP[d] = ldA(s0 + D + d);
#pragma unroll
          for (int str = 0; str < NSTR; ++str)
#pragma unroll
            for (int g = 0; g < GATES; ++g)
              bP[d][str * GATES + g] = bb[str][(size_t)((s0 + D + d) * GATES + g) * 64];
        }
      }
#pragma unroll
      for (int d = 0; d < D; ++d)
#pragma unroll
        for (int str = 0; str < NSTR; ++str)
#pragma unroll
          for (int g = 0; g < GATES; ++g)
            acc[str][g] = __builtin_amdgcn_mfma_f32_32x32x16_bf16(
                aP[d], *(bf16x8*)&bP[d][str * GATES + g], acc[str][g], 0, 0, 0);
      __builtin_amdgcn_s_setprio(0);

#pragma unroll
      for (int str = 0; str < NSTR; ++str) {
        const int jc = (MODE == 2) ? (p * 8 + str * 4 + w) : (p * 4 + w);
        const int jh = jc * 32 + (lane & 31);
        if (MODE < 2) {
          float bi = bW[jh], bo = bW[512 + jh], bu = bW[1024 + jh];
          if (MODE == 1) { bi += bU[jh]; bo += bU[512 + jh]; bu += bU[1024 + jh]; }
#pragma unroll
          for (int reg = 0; reg < 16; ++reg) {
            int rl = ((lane >> 5) << 2) + (reg & 3) + ((reg >> 2) << 3);
            int node = ids0[rl];
            if (node < 0) continue;
            size_t base = (size_t)node * 512 + jh;
            float iv = acc[str][0][reg] + bi;
            float ov = acc[str][1][reg] + bo;
            float uv = acc[str][2][reg] + bu;
            float fcv = (MODE == 1) ? bf2f(fc[base]) : 0.f;
            float cn = sigm(iv) * tfast(uv) + fcv;
            c[base] = cn;
            float hv = sigm(ov) * tfast(cn);
            h[base] = hv;
            hb[base] = f2bf(hv);
          }
        } else {
          float bfv = bW[jh] + bU[jh];
#pragma unroll
          for (int reg = 0; reg < 16; ++reg) {
            int rl = ((lane >> 5) << 2) + (reg & 3) + ((reg >> 2) << 3);
            int pe = ids0[rl];
            if (pe < 0) continue;
            int ce = ids1[rl];
            float fv = sigm(acc[str][0][reg] + bfv);
            fc[(size_t)pe * 512 + jh] = f2bf(fv * c[(size_t)ce * 512 + jh]);
          }
        }
      }
    }
  }
}

// ---------------- driver (exact R18/R19) ----------------
static void run_all(const float* x, const int* par, const int* chd,
                    const float* Wiou, const float* bWiou, const float* Uiou, const float* bUiou,
                    const float* Wf, const float* bWf, const float* Uf, const float* bUf,
                    float* h, int N, int E, void* d_ws, hipStream_t stream) {
  const size_t NV = (size_t)N * 512;
  char* cur = (char*)d_ws;
  auto take = [&](size_t bytes) -> char* {
    char* r = cur; cur += (bytes + 255) & ~(size_t)255; return r;
  };
  float* c             = (float*)take(NV * 4);
  unsigned short* hb   = (unsigned short*)take(NV * 2);
  unsigned short* hsumb= (unsigned short*)take(NV * 2);
  unsigned short* xb   = (unsigned short*)take(NV * 2);
  unsigned short* fc   = (unsigned short*)take(NV * 2);
  unsigned short* BpkI = (unsigned short*)take((size_t)16 * 64 * 3 * 64 * 8 * 2);
  unsigned short* BpkF = (unsigned short*)take((size_t)16 * 64 * 64 * 8 * 2);
  int* node_order      = (int*)take((size_t)N * 4);
  int* nodeCnt         = (int*)take(MAXIT * 4);
  int* edgeCnt         = (int*)take(MAXIT * 4);
  int* bucket          = (int*)take((size_t)N * MAXDEG * 4);
  int* nodeList        = (int*)take((size_t)MAXIT * N * 4);
  int* edgeList        = (int*)take((size_t)MAXIT * N * 4);

  kzero16<<<2048, 256, 0, stream>>>((uint4*)c, NV * 4 / 16);
  kzero16<<<2048, 256, 0, stream>>>((uint4*)hb, NV * 2 / 16);
  kzeroi<<<(N + 255) / 256, 256, 0, stream>>>(node_order, N);
  kzeroi<<<1, 64, 0, stream>>>(nodeCnt, MAXIT);
  kzeroi<<<1, 64, 0, stream>>>(edgeCnt, MAXIT);

  k_pack_x<<<2048, 256, 0, stream>>>(x, xb, NV / 8);
  k_pack_biou<<<(16 * 64 * 3 * 64 + 255) / 256, 256, 0, stream>>>(Wiou, Uiou, BpkI);
  k_pack_bf<<<(16 * 64 * 64 + 255) / 256, 256, 0, stream>>>(Wf, Uf, BpkF);

  k_histo<<<(E + 255) / 256, 256, 0, stream>>>(par, E, node_order, bucket);
  k_rank<<<(E + 255) / 256, 256, 0, stream>>>(par, E, N, node_order, bucket, edgeCnt, edgeList);
  k_nodelist<<<(N + 255) / 256, 256, 0, stream>>>(N, node_order, nodeCnt, nodeList);

  {
    int g = imin(4096, (N + 31) >> 5);
    k_gemm9<0><<<g, 256, 0, stream>>>(0, N, nodeCnt, nodeList, par, chd,
                                      xb, hsumb, BpkI, bWiou, bUiou, c, h, hb, fc);
  }
  for (int n = 1; n < MAXIT; ++n) {
    int boundE = E / n;
    int boundN = imin(N, boundE);
    int boundA = (n >= 2) ? (E / (n - 1)) : 0;
    int gE = imin(2048, (int)(((size_t)(boundE + boundA) * 64 + 255) / 256));
    int gF = imin(4096, (boundE + 31) >> 5);
    int gI = imin(4096, (boundN + 31) >> 5);
    k_edge_pre<<<gE, 256, 0, stream>>>(n, N, edgeCnt, edgeList, par, chd, node_order,
                                       hb, hsumb, fc, c);
    k_gemm9<2><<<gF, 256, 0, stream>>>(n, N, edgeCnt, edgeList, par, chd,
                                       xb, hb, BpkF, bWf, bUf, c, h, hb, fc);
    k_gemm9<1><<<gI, 256, 0, stream>>>(n, N, nodeCnt, nodeList, par, chd,
                                       xb, hsumb, BpkI, bWiou, bUiou, c, h, hb, fc);
  }
}

extern "C" void kernel_launch(void* const* d_in, const int* in_sizes, int n_in,
                              void* d_out, int out_size, void* d_ws, size_t ws_size,
                              hipStream_t stream) {
  (void)n_in; (void)out_size;
  const float* x     = (const float*)d_in[0];
  const int*   ei    = (const int*)d_in[1];
  const float* Wiou  = (const float*)d_in[4];
  const float* bWiou = (const float*)d_in[5];
  const float* Uiou  = (const float*)d_in[6];
  const float* bUiou = (const float*)d_in[7];
  const float* Wf    = (const float*)d_in[8];
  const float* bWf   = (const float*)d_in[9];
  const float* Uf    = (const float*)d_in[10];
  const float* bUf   = (const float*)d_in[11];
  const int N = in_sizes[0] / 512;
  const int E = in_sizes[1] / 2;
  const int* par = ei;
  const int* chd = ei + E;
  float* h = (float*)d_out;

  const size_t NV = (size_t)N * 512;
  const size_t need = NV * 12 + (size_t)8 * 1024 * 1024 +
                      ((size_t)N * (1 + MAXDEG + 2 * MAXIT) + 512) * 4;

  if (ws_size >= need) {
    run_all(x, par, chd, Wiou, bWiou, Uiou, bUiou, Wf, bWf, Uf, bUf,
            h, N, E, d_ws, stream);
  } else {
    kfill<<<2048, 256, 0, stream>>>(h, NV, 1.0e6f);  // diagnostic sentinel: ws too small
  }
}

// Round 21
// 2520.560 us; speedup vs baseline: 1.2284x; 1.0016x over previous
//
#include <hip/hip_runtime.h>
#include <math.h>

#define MAXIT 16      // wavefronts 0..15 (max in-degree ~13 for Poisson(2))
#define MAXDEG 16     // per-parent bucket capacity for ranking

typedef __attribute__((ext_vector_type(8))) short bf16x8;
typedef __attribute__((ext_vector_type(16))) float f32x16;

static inline int imin(int a, int b) { return a < b ? a : b; }

__device__ __forceinline__ float sigm(float v) { return 1.0f / (1.0f + __expf(-v)); }
__device__ __forceinline__ float tfast(float v) {
  float vc = fminf(fmaxf(v, -20.0f), 20.0f);
  float t = __expf(2.0f * vc);
  return (t - 1.0f) / (t + 1.0f);
}
__device__ __forceinline__ unsigned short f2bf(float f) {
  unsigned int u = __float_as_uint(f);
  u += 0x7FFFu + ((u >> 16) & 1u);
  return (unsigned short)(u >> 16);
}
__device__ __forceinline__ float bf2f(unsigned short s) {
  return __uint_as_float(((unsigned int)s) << 16);
}
__device__ __forceinline__ unsigned bfadd2(unsigned x, unsigned y) {
  float sl = bf2f((unsigned short)(x & 0xFFFFu)) + bf2f((unsigned short)(y & 0xFFFFu));
  float sh = bf2f((unsigned short)(x >> 16)) + bf2f((unsigned short)(y >> 16));
  return (unsigned)f2bf(sl) | ((unsigned)f2bf(sh) << 16);
}
__device__ __forceinline__ uint4 bfadd8(uint4 a, uint4 b) {
  return make_uint4(bfadd2(a.x, b.x), bfadd2(a.y, b.y), bfadd2(a.z, b.z), bfadd2(a.w, b.w));
}

// async global->LDS, 16B per lane; lds base must be wave-uniform (HW adds lane*16)
__device__ __forceinline__ void gload_lds16(const unsigned short* g, void* l) {
  __builtin_amdgcn_global_load_lds(
      (const __attribute__((address_space(1))) unsigned int*)g,
      (__attribute__((address_space(3))) unsigned int*)l, 16, 0, 0);
}

// ---------------- fills ----------------
__global__ void kzero16(uint4* p, size_t n) {
  size_t i = (size_t)blockIdx.x * blockDim.x + threadIdx.x;
  size_t st = (size_t)gridDim.x * blockDim.x;
  uint4 z = make_uint4(0u, 0u, 0u, 0u);
  for (; i < n; i += st) p[i] = z;
}
__global__ void kzeroi(int* p, int n) {
  int i = blockIdx.x * blockDim.x + threadIdx.x;
  if (i < n) p[i] = 0;
}
__global__ void kfill(float* p, size_t n, float v) {
  size_t i = (size_t)blockIdx.x * blockDim.x + threadIdx.x;
  size_t st = (size_t)gridDim.x * blockDim.x;
  for (; i < n; i += st) p[i] = v;
}

// ---------------- graph precompute ----------------
__global__ void k_histo(const int* __restrict__ par, int E,
                        int* __restrict__ node_order, int* __restrict__ bucket) {
  int e = blockIdx.x * blockDim.x + threadIdx.x;
  if (e >= E) return;
  int p = par[e];
  int slot = atomicAdd(&node_order[p], 1);
  if (slot < MAXDEG) bucket[(size_t)p * MAXDEG + slot] = e;
}

__global__ void k_rank(const int* __restrict__ par, int E, int N,
                       const int* __restrict__ node_order, const int* __restrict__ bucket,
                       int* __restrict__ edgeCnt, int* __restrict__ edgeList) {
  __shared__ int lcnt[MAXIT], lbase[MAXIT];
  const int t = threadIdx.x;
  if (t < MAXIT) lcnt[t] = 0;
  __syncthreads();
  int e = blockIdx.x * blockDim.x + t;
  int r = 0, ls = 0;
  if (e < E) {
    int p = par[e];
    int d = node_order[p]; if (d > MAXDEG) d = MAXDEG;
    int rr = 1;
    for (int j = 0; j < d; ++j) rr += (bucket[(size_t)p * MAXDEG + j] < e) ? 1 : 0;
    if (rr < MAXIT) { r = rr; ls = atomicAdd(&lcnt[rr], 1); }
  }
  __syncthreads();
  if (t < MAXIT && lcnt[t] > 0) lbase[t] = atomicAdd(&edgeCnt[t], lcnt[t]);
  __syncthreads();
  if (r > 0) edgeList[(size_t)r * N + lbase[r] + ls] = e;
}

__global__ void k_nodelist(int N, const int* __restrict__ node_order,
                           int* __restrict__ nodeCnt, int* __restrict__ nodeList) {
  __shared__ int lcnt[MAXIT], lbase[MAXIT];
  const int t = threadIdx.x;
  if (t < MAXIT) lcnt[t] = 0;
  __syncthreads();
  int v = blockIdx.x * blockDim.x + t;
  int n = -1, ls = 0;
  if (v < N) {
    n = node_order[v]; if (n >= MAXIT) n = MAXIT - 1;
    ls = atomicAdd(&lcnt[n], 1);
  }
  __syncthreads();
  if (t < MAXIT && lcnt[t] > 0) lbase[t] = atomicAdd(&nodeCnt[t], lcnt[t]);
  __syncthreads();
  if (n >= 0) nodeList[(size_t)n * N + lbase[n] + ls] = v;
}

// ---------------- x -> bf16 mirror ----------------
__global__ void k_pack_x(const float* __restrict__ x, unsigned short* __restrict__ xb, size_t n8) {
  size_t i = (size_t)blockIdx.x * blockDim.x + threadIdx.x;
  size_t st = (size_t)gridDim.x * blockDim.x;
  for (; i < n8; i += st) {
    const float* p = x + i * 8;
    float4 f0 = *(const float4*)p, f1 = *(const float4*)(p + 4);
    uint4 r;
    r.x = (unsigned)f2bf(f0.x) | ((unsigned)f2bf(f0.y) << 16);
    r.y = (unsigned)f2bf(f0.z) | ((unsigned)f2bf(f0.w) << 16);
    r.z = (unsigned)f2bf(f1.x) | ((unsigned)f2bf(f1.y) << 16);
    r.w = (unsigned)f2bf(f1.z) | ((unsigned)f2bf(f1.w) << 16);
    *(uint4*)(xb + i * 8) = r;
  }
}

// ---------------- weight packs: jc-contiguous fragment-linear B (R11/R12-verified) ----------------
__global__ void k_pack_biou(const float* __restrict__ W, const float* __restrict__ U,
                            unsigned short* __restrict__ Bpk) {
  int i = blockIdx.x * blockDim.x + threadIdx.x;
  if (i >= 16 * 64 * 3 * 64) return;
  int lane = i & 63;
  int q = i >> 6;
  int g = q % 3; q /= 3;
  int s = q & 63;
  int jc = q >> 6;
  int col = jc * 32 + (lane & 31);
  int k0 = s * 16 + (lane >> 5) * 8;
  int rowW = g * 512 + col;
  unsigned short v[8];
#pragma unroll
  for (int j = 0; j < 8; ++j) {
    int kk = k0 + j;
    v[j] = f2bf(kk < 512 ? W[(size_t)rowW * 512 + kk] : U[(size_t)rowW * 512 + kk - 512]);
  }
  *(uint4*)(Bpk + (size_t)i * 8) = *(uint4*)v;
}

__global__ void k_pack_bf(const float* __restrict__ W, const float* __restrict__ U,
                          unsigned short* __restrict__ Bpk) {
  int i = blockIdx.x * blockDim.x + threadIdx.x;
  if (i >= 16 * 64 * 64) return;
  int lane = i & 63;
  int q = i >> 6;
  int s = q & 63;
  int jc = q >> 6;
  int col = jc * 32 + (lane & 31);
  int k0 = s * 16 + (lane >> 5) * 8;
  unsigned short v[8];
#pragma unroll
  for (int j = 0; j < 8; ++j) {
    int kk = k0 + j;
    v[j] = f2bf(kk < 512 ? W[(size_t)col * 512 + kk] : U[(size_t)col * 512 + kk - 512]);
  }
  *(uint4*)(Bpk + (size_t)i * 8) = *(uint4*)v;
}

// ---------------- fused: addfc(n-1) for deg>n-1 parents + hsumb(n) ----------------
__global__ void k_edge_pre(int n, int N, const int* __restrict__ edgeCnt, const int* __restrict__ edgeList,
                           const int* __restrict__ par, const int* __restrict__ chd,
                           const int* __restrict__ node_order,
                           const unsigned short* __restrict__ hb, unsigned short* __restrict__ hsumb,
                           const unsigned short* __restrict__ fc, float* __restrict__ c) {
  const int cntH = edgeCnt[n];
  const int cntA = (n >= 2) ? edgeCnt[n - 1] : 0;
  const size_t totH = (size_t)cntH * 64;
  const size_t total = totH + (size_t)cntA * 64;
  size_t st = (size_t)gridDim.x * blockDim.x;
  for (size_t i = (size_t)blockIdx.x * blockDim.x + threadIdx.x; i < total; i += st) {
    if (i < totH) {
      int slot = (int)(i >> 6), j8 = ((int)i & 63) << 3;
      int e = edgeList[(size_t)n * N + slot];
      int p = par[e], ch = chd[e];
      uint4 hv = *(const uint4*)&hb[(size_t)ch * 512 + j8];
      if (n == 1) {
        *(uint4*)&hsumb[(size_t)p * 512 + j8] = hv;
      } else {
        uint4 hs = *(const uint4*)&hsumb[(size_t)p * 512 + j8];
        *(uint4*)&hsumb[(size_t)p * 512 + j8] = bfadd8(hs, hv);
      }
    } else {
      size_t k = i - totH;
      int slot = (int)(k >> 6), j8 = ((int)k & 63) << 3;
      int e = edgeList[(size_t)(n - 1) * N + slot];
      int p = par[e];
      if (node_order[p] <= n - 1) continue;   // deg==n-1 handled in iou epilogue
      size_t base = (size_t)p * 512 + j8;
      uint4 f8 = *(const uint4*)&fc[base];
      unsigned fw[4] = {f8.x, f8.y, f8.z, f8.w};
      float4 c0 = *(const float4*)&c[base];
      float4 c1 = *(const float4*)&c[base + 4];
      c0.x += bf2f((unsigned short)(fw[0] & 0xFFFFu)); c0.y += bf2f((unsigned short)(fw[0] >> 16));
      c0.z += bf2f((unsigned short)(fw[1] & 0xFFFFu)); c0.w += bf2f((unsigned short)(fw[1] >> 16));
      c1.x += bf2f((unsigned short)(fw[2] & 0xFFFFu)); c1.y += bf2f((unsigned short)(fw[2] >> 16));
      c1.z += bf2f((unsigned short)(fw[3] & 0xFFFFu)); c1.w += bf2f((unsigned short)(fw[3] >> 16));
      *(float4*)&c[base] = c0;
      *(float4*)&c[base + 4] = c1;
    }
  }
}

// ---------------- A-resident MFMA GEMM: coalesced DMA staging (row-major LDS, kc8-XOR) ----------------
// MODE 0: iou wavefront 0 (K=512: xb; bias W; 32KB LDS)
// MODE 1: iou n>=1      (K=1024: [xb | hsumb]; bias W+U; +fc; writes c,h,hb)
// MODE 2: f GEMM        (K=1024: [xb[par] | hb[chd]]; fc[par]=sigm(acc+b)*c[chd])
// R20-verified: VGPR 100, no spill, clean 197/86MB traffic, setprio kept.
template<int MODE>
__global__ __launch_bounds__(256, 2)
void k_gemm9(int n, int N, const int* __restrict__ cntArr, const int* __restrict__ list,
             const int* __restrict__ par, const int* __restrict__ chd,
             const unsigned short* __restrict__ xb, const unsigned short* __restrict__ hsrc,
             const unsigned short* __restrict__ Bpk,
             const float* __restrict__ bW, const float* __restrict__ bU,
             float* __restrict__ c, float* __restrict__ h, unsigned short* __restrict__ hb,
             unsigned short* __restrict__ fc) {
  const int cnt = cntArr[n];
  if (cnt == 0) return;
  constexpr int KS    = (MODE == 0) ? 32 : 64;
  constexpr int KC8   = KS * 2;                  // 16B chunks per row
  constexpr int GATES = (MODE == 2) ? 1 : 3;
  constexpr int NSTR  = (MODE == 2) ? 2 : 1;
  constexpr int NPASS = (MODE == 2) ? 2 : 4;
  constexpr int D     = 4;
  const int rowTiles = (cnt + 31) >> 5;

  __shared__ uint4 lA4[32 * KC8];
  __shared__ int ids0[32], ids1[32];
  const int t = threadIdx.x, lane = t & 63, w = t >> 6;

  auto ldA = [&](int s) -> bf16x8 {
    int row = lane & 31;
    int kc8 = 2 * s + (lane >> 5);
    return *(const bf16x8*)&lA4[row * KC8 + (kc8 ^ (row & 7))];
  };

  for (int tile = blockIdx.x; tile < rowTiles; tile += gridDim.x) {
    __syncthreads();
    if (t < 32) {
      int r = (tile << 5) + t;
      int idx = (r < cnt) ? list[(size_t)n * N + r] : -1;
      if (MODE == 2) { ids0[t] = idx >= 0 ? par[idx] : -1; ids1[t] = idx >= 0 ? chd[idx] : 0; }
      else           { ids0[t] = idx; ids1[t] = 0; }
    }
    __syncthreads();

    // ---- stage A: async DMA, coalesced (one row x 64 consecutive chunks per wave) ----
    constexpr int ITERS = (32 * KC8) / 256;      // 8 or 16
#pragma unroll
    for (int i = 0; i < ITERS; ++i) {
      int slot = i * 256 + t;
      int row = slot >> ((MODE == 0) ? 6 : 7);   // wave-uniform
      int col = slot & (KC8 - 1);
      int kc8 = col ^ (row & 7);                 // pre-swizzled global chunk
      const unsigned short* gp;
      if (MODE == 0 || col < 64) {               // wave-uniform branch (bit6 XOR-invariant)
        int id0 = ids0[row];
        gp = xb + (size_t)(id0 < 0 ? 0 : id0) * 512 + (kc8 << 3);
      } else {
        int idh;
        if (MODE == 2) { idh = ids1[row]; }
        else { int id0 = ids0[row]; idh = id0 < 0 ? 0 : id0; }
        gp = hsrc + (size_t)idh * 512 + ((kc8 - 64) << 3);
      }
      gload_lds16(gp, &lA4[i * 256 + (t & ~63)]);   // wave-uniform LDS base, linear dest
    }
    __syncthreads();                      // drains vmcnt before compute

    for (int p = 0; p < NPASS; ++p) {
      const uint4* bb[NSTR];
#pragma unroll
      for (int str = 0; str < NSTR; ++str) {
        int jc = (MODE == 2) ? (p * 8 + str * 4 + w) : (p * 4 + w);
        bb[str] = (const uint4*)Bpk + (size_t)jc * 64 * GATES * 64 + lane;
      }
      f32x16 acc[NSTR][GATES];
#pragma unroll
      for (int str = 0; str < NSTR; ++str)
#pragma unroll
        for (int g = 0; g < GATES; ++g)
#pragma unroll
          for (int q = 0; q < 16; ++q) acc[str][g][q] = 0.f;

      bf16x8 aP[D];
      uint4 bP[D][NSTR * GATES];
#pragma unroll
      for (int d = 0; d < D; ++d) {
        aP[d] = ldA(d);
#pragma unroll
        for (int str = 0; str < NSTR; ++str)
#pragma unroll
          for (int g = 0; g < GATES; ++g)
            bP[d][str * GATES + g] = bb[str][(size_t)(d * GATES + g) * 64];
      }
      __builtin_amdgcn_s_setprio(1);      // favor compute-phase wave on this SIMD
      for (int s0 = 0; s0 < KS - D; s0 += D) {
#pragma unroll
        for (int d = 0; d < D; ++d) {
#pragma unroll
          for (int str = 0; str < NSTR; ++str)
#pragma unroll
            for (int g = 0; g < GATES; ++g)
              acc[str][g] = __builtin_amdgcn_mfma_f32_32x32x16_bf16(
                  aP[d], *(bf16x8*)&bP[d][str * GATES + g], acc[str][g], 0, 0, 0);
          aP[d] = ldA(s0 + D + d);
#pragma unroll
          for (int str = 0; str < NSTR; ++str)
#pragma unroll
            for (int g = 0; g < GATES; ++g)
              bP[d][str * GATES + g] = bb[str][(size_t)((s0 + D + d) * GATES + g) * 64];
        }
      }
#pragma unroll
      for (int d = 0; d < D; ++d)
#pragma unroll
        for (int str = 0; str < NSTR; ++str)
#pragma unroll
          for (int g = 0; g < GATES; ++g)
            acc[str][g] = __builtin_amdgcn_mfma_f32_32x32x16_bf16(
                aP[d], *(bf16x8*)&bP[d][str * GATES + g], acc[str][g], 0, 0, 0);
      __builtin_amdgcn_s_setprio(0);

#pragma unroll
      for (int str = 0; str < NSTR; ++str) {
        const int jc = (MODE == 2) ? (p * 8 + str * 4 + w) : (p * 4 + w);
        const int jh = jc * 32 + (lane & 31);
        if (MODE < 2) {
          float bi = bW[jh], bo = bW[512 + jh], bu = bW[1024 + jh];
          if (MODE == 1) { bi += bU[jh]; bo += bU[512 + jh]; bu += bU[1024 + jh]; }
#pragma unroll
          for (int reg = 0; reg < 16; ++reg) {
            int rl = ((lane >> 5) << 2) + (reg & 3) + ((reg >> 2) << 3);
            int node = ids0[rl];
            if (node < 0) continue;
            size_t base = (size_t)node * 512 + jh;
            float iv = acc[str][0][reg] + bi;
            float ov = acc[str][1][reg] + bo;
            float uv = acc[str][2][reg] + bu;
            float fcv = (MODE == 1) ? bf2f(fc[base]) : 0.f;
            float cn = sigm(iv) * tfast(uv) + fcv;
            c[base] = cn;
            float hv = sigm(ov) * tfast(cn);
            h[base] = hv;
            hb[base] = f2bf(hv);
          }
        } else {
          float bfv = bW[jh] + bU[jh];
#pragma unroll
          for (int reg = 0; reg < 16; ++reg) {
            int rl = ((lane >> 5) << 2) + (reg & 3) + ((reg >> 2) << 3);
            int pe = ids0[rl];
            if (pe < 0) continue;
            int ce = ids1[rl];
            float fv = sigm(acc[str][0][reg] + bfv);
            fc[(size_t)pe * 512 + jh] = f2bf(fv * c[(size_t)ce * 512 + jh]);
          }
        }
      }
    }
  }
}

// ---------------- driver ----------------
static void run_all(const float* x, const int* par, const int* chd,
                    const float* Wiou, const float* bWiou, const float* Uiou, const float* bUiou,
                    const float* Wf, const float* bWf, const float* Uf, const float* bUf,
                    float* h, int N, int E, void* d_ws, hipStream_t stream) {
  const size_t NV = (size_t)N * 512;
  char* cur = (char*)d_ws;
  auto take = [&](size_t bytes) -> char* {
    char* r = cur; cur += (bytes + 255) & ~(size_t)255; return r;
  };
  float* c             = (float*)take(NV * 4);        // NV*4 is 256-multiple ->
  unsigned short* hb   = (unsigned short*)take(NV * 2); // hb contiguous with c
  unsigned short* hsumb= (unsigned short*)take(NV * 2);
  unsigned short* xb   = (unsigned short*)take(NV * 2);
  unsigned short* fc   = (unsigned short*)take(NV * 2);
  unsigned short* BpkI = (unsigned short*)take((size_t)16 * 64 * 3 * 64 * 8 * 2);
  unsigned short* BpkF = (unsigned short*)take((size_t)16 * 64 * 64 * 8 * 2);
  int* meta            = (int*)take(((size_t)N + 32) * 4);  // node_order | nodeCnt | edgeCnt
  int* node_order      = meta;
  int* nodeCnt         = meta + N;
  int* edgeCnt         = meta + N + MAXIT;
  int* bucket          = (int*)take((size_t)N * MAXDEG * 4);
  int* nodeList        = (int*)take((size_t)MAXIT * N * 4);
  int* edgeList        = (int*)take((size_t)MAXIT * N * 4);

  // fused zero: c (fp32) + hb (bf16) in one contiguous 300MB pass; meta in one kzeroi
  kzero16<<<2048, 256, 0, stream>>>((uint4*)c, (NV * 4 + NV * 2) / 16);
  kzeroi<<<(N + 32 + 255) / 256, 256, 0, stream>>>(meta, N + 32);

  k_pack_x<<<2048, 256, 0, stream>>>(x, xb, NV / 8);
  k_pack_biou<<<(16 * 64 * 3 * 64 + 255) / 256, 256, 0, stream>>>(Wiou, Uiou, BpkI);
  k_pack_bf<<<(16 * 64 * 64 + 255) / 256, 256, 0, stream>>>(Wf, Uf, BpkF);

  k_histo<<<(E + 255) / 256, 256, 0, stream>>>(par, E, node_order, bucket);
  k_rank<<<(E + 255) / 256, 256, 0, stream>>>(par, E, N, node_order, bucket, edgeCnt, edgeList);
  k_nodelist<<<(N + 255) / 256, 256, 0, stream>>>(N, node_order, nodeCnt, nodeList);

  {
    int g = imin(4096, (N + 31) >> 5);
    k_gemm9<0><<<g, 256, 0, stream>>>(0, N, nodeCnt, nodeList, par, chd,
                                      xb, hsumb, BpkI, bWiou, bUiou, c, h, hb, fc);
  }
  for (int n = 1; n < MAXIT; ++n) {
    int boundE = E / n;
    int boundN = imin(N, boundE);
    int boundA = (n >= 2) ? (E / (n - 1)) : 0;
    int gE = imin(2048, (int)(((size_t)(boundE + boundA) * 64 + 255) / 256));
    int gF = imin(4096, (boundE + 31) >> 5);
    int gI = imin(4096, (boundN + 31) >> 5);
    k_edge_pre<<<gE, 256, 0, stream>>>(n, N, edgeCnt, edgeList, par, chd, node_order,
                                       hb, hsumb, fc, c);
    k_gemm9<2><<<gF, 256, 0, stream>>>(n, N, edgeCnt, edgeList, par, chd,
                                       xb, hb, BpkF, bWf, bUf, c, h, hb, fc);
    k_gemm9<1><<<gI, 256, 0, stream>>>(n, N, nodeCnt, nodeList, par, chd,
                                       xb, hsumb, BpkI, bWiou, bUiou, c, h, hb, fc);
  }
}

extern "C" void kernel_launch(void* const* d_in, const int* in_sizes, int n_in,
                              void* d_out, int out_size, void* d_ws, size_t ws_size,
                              hipStream_t stream) {
  (void)n_in; (void)out_size;
  const float* x     = (const float*)d_in[0];
  const int*   ei    = (const int*)d_in[1];
  const float* Wiou  = (const float*)d_in[4];
  const float* bWiou = (const float*)d_in[5];
  const float* Uiou  = (const float*)d_in[6];
  const float* bUiou = (const float*)d_in[7];
  const float* Wf    = (const float*)d_in[8];
  const float* bWf   = (const float*)d_in[9];
  const float* Uf    = (const float*)d_in[10];
  const float* bUf   = (const float*)d_in[11];
  const int N = in_sizes[0] / 512;
  const int E = in_sizes[1] / 2;
  const int* par = ei;
  const int* chd = ei + E;
  float* h = (float*)d_out;

  const size_t NV = (size_t)N * 512;
  const size_t need = NV * 12 + (size_t)8 * 1024 * 1024 +
                      ((size_t)N * (1 + MAXDEG + 2 * MAXIT) + 512) * 4;

  if (ws_size >= need) {
    run_all(x, par, chd, Wiou, bWiou, Uiou, bUiou, Wf, bWf, Uf, bUf,
            h, N, E, d_ws, stream);
  } else {
    kfill<<<2048, 256, 0, stream>>>(h, NV, 1.0e6f);  // diagnostic sentinel: ws too small
  }
}